// Round 1
// baseline (3438.442 us; speedup 1.0000x reference)
//
#include <hip/hip_runtime.h>
#include <hip/hip_bf16.h>
#include <cstdint>
#include <cstddef>

#define B_  16
#define N_  4096
#define M_  512
#define KNB 16

// ---------------------------------------------------------------------------
// FPS: one block per batch. x[b] staged in LDS; 511 serial argmax iterations.
// Distance arithmetic uses __fmul_rn/__fadd_rn to forbid FMA contraction so the
// f32 values match numpy's (dx*dx + dy*dy + dz*dz) exactly; argmax ties -> lowest index.
// ---------------------------------------------------------------------------
__global__ __launch_bounds__(512) void fps_kernel(const float* __restrict__ x,
                                                  float* __restrict__ pts) {
  __shared__ float xs[N_ * 3];
  __shared__ float rv[8];
  __shared__ int   ri[8];
  __shared__ float cur[3];
  const int b = blockIdx.x, t = threadIdx.x;
  const float* xb = x + (size_t)b * N_ * 3;
  for (int s = t; s < N_ * 3; s += 512) xs[s] = xb[s];
  __syncthreads();

  float px[8], py[8], pz[8], dm[8];
#pragma unroll
  for (int j = 0; j < 8; ++j) {
    int p = t + j * 512;
    px[j] = xs[p * 3 + 0];
    py[j] = xs[p * 3 + 1];
    pz[j] = xs[p * 3 + 2];
    dm[j] = __builtin_inff();
  }
  float cx = xs[0], cy = xs[1], cz = xs[2];
  if (t == 0) {
    pts[(size_t)b * M_ * 3 + 0] = cx;
    pts[(size_t)b * M_ * 3 + 1] = cy;
    pts[(size_t)b * M_ * 3 + 2] = cz;
  }
  const int lane = t & 63, w = t >> 6;
  for (int i = 1; i < M_; ++i) {
    float bv = -1.f;
    int bi = 0;
#pragma unroll
    for (int j = 0; j < 8; ++j) {
      float dx = px[j] - cx, dy = py[j] - cy, dz = pz[j] - cz;
      float d = __fmul_rn(dx, dx);
      d = __fadd_rn(d, __fmul_rn(dy, dy));
      d = __fadd_rn(d, __fmul_rn(dz, dz));
      float m2 = fminf(dm[j], d);
      dm[j] = m2;
      int p = t + j * 512;
      if (m2 > bv || (m2 == bv && p < bi)) { bv = m2; bi = p; }
    }
#pragma unroll
    for (int off = 32; off >= 1; off >>= 1) {
      float ov = __shfl_xor(bv, off);
      int   oi = __shfl_xor(bi, off);
      if (ov > bv || (ov == bv && oi < bi)) { bv = ov; bi = oi; }
    }
    if (lane == 0) { rv[w] = bv; ri[w] = bi; }
    __syncthreads();
    if (t == 0) {
      float v = rv[0];
      int s_ = ri[0];
      for (int q = 1; q < 8; ++q)
        if (rv[q] > v || (rv[q] == v && ri[q] < s_)) { v = rv[q]; s_ = ri[q]; }
      float a0 = xs[s_ * 3 + 0], a1 = xs[s_ * 3 + 1], a2 = xs[s_ * 3 + 2];
      cur[0] = a0; cur[1] = a1; cur[2] = a2;
      pts[((size_t)b * M_ + i) * 3 + 0] = a0;
      pts[((size_t)b * M_ + i) * 3 + 1] = a1;
      pts[((size_t)b * M_ + i) * 3 + 2] = a2;
    }
    __syncthreads();
    cx = cur[0]; cy = cur[1]; cz = cur[2];
  }
}

// ---------------------------------------------------------------------------
// kNN: f is [B, M, C] row-major. 16 blocks per batch, whole f[b] staged in LDS
// (transposed float4 layout, padded to dodge bank conflicts). One wave per row,
// 16 rounds of masked wave-argmin (ties -> lowest index; order of k irrelevant
// downstream since everything is permutation-invariant over k).
// d = (sq_m - 2*dot) + sq_j, same formula/order as the reference.
// ---------------------------------------------------------------------------
template <int C>
__global__ __launch_bounds__(256) void knn_kernel(const float* __restrict__ f,
                                                  int* __restrict__ knn) {
  constexpr int C4 = (C + 3) / 4;
  __shared__ float4 ls4[C4 * 513];
  float* lss = (float*)ls4;
  const int b = blockIdx.x >> 4;
  const int mb = (blockIdx.x & 15) * 32;
  const int t = threadIdx.x, lane = t & 63, w = t >> 6;
  const float* fb = f + (size_t)b * M_ * C;
  if (C & 3) {
    for (int j = t; j < M_; j += 256)
      for (int cc = (C & 3); cc < 4; ++cc)
        lss[((C4 - 1) * 513 + j) * 4 + cc] = 0.f;
  }
  for (int s = t; s < M_ * C; s += 256) {
    int j = s / C, c = s % C;
    lss[((c >> 2) * 513 + j) * 4 + (c & 3)] = fb[s];
  }
  __syncthreads();

  float sqj[8];
#pragma unroll
  for (int jj = 0; jj < 8; ++jj) {
    int j = lane + 64 * jj;
    float a = 0.f;
    for (int c4 = 0; c4 < C4; ++c4) {
      float4 v = ls4[c4 * 513 + j];
      a += v.x * v.x + v.y * v.y + v.z * v.z + v.w * v.w;
    }
    sqj[jj] = a;
  }

  for (int rr = 0; rr < 8; ++rr) {
    const int m = mb + w * 8 + rr;
    float sqm = 0.f;
    for (int c4 = 0; c4 < C4; ++c4) {
      float4 v = ls4[c4 * 513 + m];
      sqm += v.x * v.x + v.y * v.y + v.z * v.z + v.w * v.w;
    }
    float dot[8] = {0.f, 0.f, 0.f, 0.f, 0.f, 0.f, 0.f, 0.f};
    for (int c4 = 0; c4 < C4; ++c4) {
      float4 fm = ls4[c4 * 513 + m];
#pragma unroll
      for (int jj = 0; jj < 8; ++jj) {
        float4 fj = ls4[c4 * 513 + lane + 64 * jj];
        dot[jj] += fm.x * fj.x + fm.y * fj.y + fm.z * fj.z + fm.w * fj.w;
      }
    }
    float d[8];
#pragma unroll
    for (int jj = 0; jj < 8; ++jj) d[jj] = (sqm - 2.f * dot[jj]) + sqj[jj];

    unsigned used = 0;
    int* out = knn + ((size_t)b * M_ + m) * KNB;
    for (int kk = 0; kk < KNB; ++kk) {
      float bv = __builtin_inff();
      int bi = 0x7fffffff;
#pragma unroll
      for (int jj = 0; jj < 8; ++jj) {
        if (!(used & (1u << jj))) {
          int j = lane + 64 * jj;
          if (d[jj] < bv || (d[jj] == bv && j < bi)) { bv = d[jj]; bi = j; }
        }
      }
#pragma unroll
      for (int off = 32; off >= 1; off >>= 1) {
        float ov = __shfl_xor(bv, off);
        int   oi = __shfl_xor(bi, off);
        if (ov < bv || (ov == bv && oi < bi)) { bv = ov; bi = oi; }
      }
      if ((bi & 63) == lane) used |= 1u << (bi >> 6);
      if (lane == 0) out[kk] = bi;
    }
  }
}

// ---------------------------------------------------------------------------
// Edge feature build: gf row (b,m,k) = [f[nbr]-f[m] ; f[m]] (2C), rel = pts[nbr]-pts[m].
// One wave per row, 4 rows per wave.
// ---------------------------------------------------------------------------
__global__ __launch_bounds__(256) void build_gf_kernel(const float* __restrict__ f,
                                                       const float* __restrict__ pts,
                                                       const int* __restrict__ idx,
                                                       float* __restrict__ gf,
                                                       float* __restrict__ rel,
                                                       int C, int bc0) {
  const int lane = threadIdx.x & 63;
  const int wave = blockIdx.x * 4 + (threadIdx.x >> 6);
#pragma unroll
  for (int s = 0; s < 4; ++s) {
    const int r = wave * 4 + s;              // chunk-local row
    const int gr = bc0 * (M_ * KNB) + r;     // global row (= linear idx index)
    const int nbr = idx[gr];
    const int bm = gr >> 4;                  // b*M + m
    const int b = gr >> 13;
    const int base_m = bm * C;
    const int base_n = (b * M_ + nbr) * C;
    float* grow = gf + (size_t)r * (2 * C);
    for (int c = lane; c < C; c += 64) grow[c] = f[base_n + c] - f[base_m + c];
    for (int c = lane; c < C; c += 64) grow[C + c] = f[base_m + c];
    if (lane < 3)
      rel[(size_t)r * 3 + lane] = pts[(size_t)(b * M_ + nbr) * 3 + lane] - pts[(size_t)bm * 3 + lane];
  }
}

// ---------------------------------------------------------------------------
// Generic fp32 GEMM: Cmat[r][n] = act( sum_k A[r][k] * W[n][k] ).
// 64x64 tile, 256 threads, 4x4 per thread, BK=16 LDS staging (padded stride 68).
// R (rows) and N are multiples of 64; K arbitrary (zero-padded tail).
// ---------------------------------------------------------------------------
template <int RELU>
__global__ __launch_bounds__(256) void gemm_kernel(const float* __restrict__ A,
                                                   const float* __restrict__ W,
                                                   float* __restrict__ Cmat,
                                                   int N, int K) {
  __shared__ float As[16][68];
  __shared__ float Ws[16][68];
  const int t = threadIdx.x;
  const int r0 = blockIdx.x * 64;
  const int n0 = blockIdx.y * 64;
  const int tr = t >> 4, tc = t & 15;
  float acc[4][4] = {};
  for (int k0 = 0; k0 < K; k0 += 16) {
#pragma unroll
    for (int s = 0; s < 4; ++s) {
      int id = t + s * 256;
      int kk = id & 15, rr = id >> 4;
      As[kk][rr] = (k0 + kk < K) ? A[(size_t)(r0 + rr) * K + k0 + kk] : 0.f;
      Ws[kk][rr] = (k0 + kk < K) ? W[(size_t)(n0 + rr) * K + k0 + kk] : 0.f;
    }
    __syncthreads();
#pragma unroll
    for (int kk = 0; kk < 16; ++kk) {
      float4 a = *(const float4*)&As[kk][tr * 4];
      float4 bq = *(const float4*)&Ws[kk][tc * 4];
      acc[0][0] += a.x * bq.x; acc[0][1] += a.x * bq.y; acc[0][2] += a.x * bq.z; acc[0][3] += a.x * bq.w;
      acc[1][0] += a.y * bq.x; acc[1][1] += a.y * bq.y; acc[1][2] += a.y * bq.z; acc[1][3] += a.y * bq.w;
      acc[2][0] += a.z * bq.x; acc[2][1] += a.z * bq.y; acc[2][2] += a.z * bq.z; acc[2][3] += a.z * bq.w;
      acc[3][0] += a.w * bq.x; acc[3][1] += a.w * bq.y; acc[3][2] += a.w * bq.z; acc[3][3] += a.w * bq.w;
    }
    __syncthreads();
  }
#pragma unroll
  for (int i = 0; i < 4; ++i) {
    int row = r0 + tr * 4 + i;
    float4 o;
    o.x = acc[i][0]; o.y = acc[i][1]; o.z = acc[i][2]; o.w = acc[i][3];
    if (RELU) {
      o.x = fmaxf(o.x, 0.f); o.y = fmaxf(o.y, 0.f);
      o.z = fmaxf(o.z, 0.f); o.w = fmaxf(o.w, 0.f);
    }
    *(float4*)&Cmat[(size_t)row * N + n0 + tc * 4] = o;
  }
}

// u += pe ; v += pe  (elementwise, float4)
__global__ void add2_kernel(float* __restrict__ u, float* __restrict__ v,
                            const float* __restrict__ pe, int n4) {
  int i = blockIdx.x * blockDim.x + threadIdx.x;
  if (i < n4) {
    float4 p = ((const float4*)pe)[i];
    float4 a = ((float4*)u)[i];
    float4 b = ((float4*)v)[i];
    a.x += p.x; a.y += p.y; a.z += p.z; a.w += p.w;
    b.x += p.x; b.y += p.y; b.z += p.z; b.w += p.w;
    ((float4*)u)[i] = a;
    ((float4*)v)[i] = b;
  }
}

__global__ void wsub_kernel(float* __restrict__ o, const float* __restrict__ a,
                            const float* __restrict__ b, int n) {
  int i = blockIdx.x * blockDim.x + threadIdx.x;
  if (i < n) o[i] = a[i] - b[i];
}

// softmax over k (16 neighbors) per (b,m,d), then weighted sum with w = v+pe.
// One block per position p (chunk-local), D threads.
__global__ void softmax_kernel(const float* __restrict__ logits,
                               const float* __restrict__ w,
                               float* __restrict__ xout, int D, int gpos0) {
  const int p = blockIdx.x;
  const int d = threadIdx.x;
  const size_t r0 = (size_t)p * KNB;
  float l[KNB];
  float mx = -__builtin_inff();
#pragma unroll
  for (int k = 0; k < KNB; ++k) {
    l[k] = logits[(r0 + k) * D + d];
    mx = fmaxf(mx, l[k]);
  }
  float s = 0.f;
#pragma unroll
  for (int k = 0; k < KNB; ++k) {
    l[k] = expf(l[k] - mx);
    s += l[k];
  }
  float acc = 0.f;
#pragma unroll
  for (int k = 0; k < KNB; ++k) acc += l[k] * w[(r0 + k) * D + d];
  xout[(size_t)(gpos0 + p) * D + d] = acc / s;
}

// Final pool: out[b][c] = max_m feat[c], out[b][256+c] = mean_m feat[c].
__global__ __launch_bounds__(256) void final_kernel(const float* __restrict__ x1,
                                                    const float* __restrict__ x2,
                                                    const float* __restrict__ x3,
                                                    float* __restrict__ out) {
  const int b = blockIdx.x, c = threadIdx.x;
  const float* p;
  int D, dc;
  if (c < 64)        { p = x1 + (size_t)b * M_ * 64;  D = 64;  dc = c; }
  else if (c < 128)  { p = x2 + (size_t)b * M_ * 64;  D = 64;  dc = c - 64; }
  else               { p = x3 + (size_t)b * M_ * 128; D = 128; dc = c - 128; }
  float mx = -__builtin_inff(), sm = 0.f;
  for (int m = 0; m < M_; ++m) {
    float v = p[(size_t)m * D + dc];
    mx = fmaxf(mx, v);
    sm += v;
  }
  out[(size_t)b * 512 + c] = mx;
  out[(size_t)b * 512 + 256 + c] = sm * (1.f / 512.f);
}

// ---------------------------------------------------------------------------
extern "C" void kernel_launch(void* const* d_in, const int* in_sizes, int n_in,
                              void* d_out, int out_size, void* d_ws, size_t ws_size,
                              hipStream_t stream) {
  const float* x = (const float*)d_in[0];
  const float* W[21];
  for (int i = 0; i < 21; ++i) W[i] = (const float*)d_in[1 + i];

  float* ws = (float*)d_ws;
  size_t off = 0;
  auto alloc = [&](size_t n) { float* p = ws + off; off += n; return p; };

  float* pts  = alloc((size_t)B_ * M_ * 3 + 16);
  float* x1   = alloc((size_t)B_ * M_ * 64);
  float* x2   = alloc((size_t)B_ * M_ * 64);
  float* x3   = alloc((size_t)B_ * M_ * 128);
  int*   idxb = (int*)alloc((size_t)B_ * M_ * KNB);
  float* wqk1 = alloc(64 * 6);
  float* wqk2 = alloc(64 * 128);
  float* wqk3 = alloc(128 * 128);

  // dynamic batch-chunking so scratch fits ws_size (deterministic in ws_size)
  size_t fixedf = off;
  int Bc = 16;
  while (Bc > 1 && (fixedf + (size_t)Bc * 8192 * 1027 + 64) * 4 > ws_size) Bc >>= 1;
  const size_t Rc = (size_t)Bc * 8192;  // rows per chunk = Bc*M*K

  float* gfa1 = alloc(Rc * 512);  // gf (<=Rc*128) then a1 (<=Rc*512)
  float* relb = alloc(Rc * 3);
  float* u0   = alloc(Rc * 128);
  float* vb   = alloc(Rc * 128);
  float* hb   = alloc(Rc * 128);  // h, then logits
  float* peb  = alloc(Rc * 128);

  fps_kernel<<<B_, 512, 0, stream>>>(x, pts);

  wsub_kernel<<<(64 * 6 + 255) / 256, 256, 0, stream>>>(wqk1, W[0], W[1], 64 * 6);
  wsub_kernel<<<(64 * 128 + 255) / 256, 256, 0, stream>>>(wqk2, W[7], W[8], 64 * 128);
  wsub_kernel<<<(128 * 128 + 255) / 256, 256, 0, stream>>>(wqk3, W[14], W[15], 128 * 128);

  struct Layer {
    const float* f; int C, D, H;
    const float *wqk, *wv, *p1, *p2, *a1, *a2;
    float* xout;
  };
  Layer ls[3] = {
      {pts, 3, 64, 256, wqk1, W[2], W[3], W[4], W[5], W[6], x1},
      {x1, 64, 64, 256, wqk2, W[9], W[10], W[11], W[12], W[13], x2},
      {x2, 64, 128, 512, wqk3, W[16], W[17], W[18], W[19], W[20], x3},
  };

  for (int li = 0; li < 3; ++li) {
    const Layer& L = ls[li];
    if (L.C == 3) knn_kernel<3><<<B_ * 16, 256, 0, stream>>>(L.f, idxb);
    else          knn_kernel<64><<<B_ * 16, 256, 0, stream>>>(L.f, idxb);

    for (int c0 = 0; c0 < B_; c0 += Bc) {
      const int rows = Bc * 8192;
      build_gf_kernel<<<rows / 16, 256, 0, stream>>>(L.f, pts, idxb, gfa1, relb, L.C, c0);

      const int twoC = 2 * L.C;
      dim3 gD(rows / 64, L.D / 64);
      gemm_kernel<0><<<gD, 256, 0, stream>>>(gfa1, L.wqk, u0, L.D, twoC);  // q - k
      gemm_kernel<0><<<gD, 256, 0, stream>>>(gfa1, L.wv, vb, L.D, twoC);   // v
      gemm_kernel<1><<<gD, 256, 0, stream>>>(relb, L.p1, hb, L.D, 3);      // relu(P1 rel)
      gemm_kernel<0><<<gD, 256, 0, stream>>>(hb, L.p2, peb, L.D, L.D);     // pe

      add2_kernel<<<(rows * L.D / 4 + 255) / 256, 256, 0, stream>>>(u0, vb, peb, rows * L.D / 4);

      dim3 gH(rows / 64, L.H / 64);
      gemm_kernel<1><<<gH, 256, 0, stream>>>(u0, L.a1, gfa1, L.H, L.D);    // relu(A1 u)
      gemm_kernel<0><<<gD, 256, 0, stream>>>(gfa1, L.a2, hb, L.D, L.H);    // logits

      softmax_kernel<<<Bc * M_, L.D, 0, stream>>>(hb, vb, L.xout, L.D, c0 * M_);
    }
  }

  final_kernel<<<B_, 256, 0, stream>>>(x1, x2, x3, (float*)d_out);
}

// Round 4
// 3347.686 us; speedup vs baseline: 1.0271x; 1.0271x over previous
//
#include <hip/hip_runtime.h>
#include <cstdint>
#include <cstddef>

#define B_  16
#define N_  4096
#define M_  512
#define KNB 16
#define P_  (B_ * M_)
#define ROWS_ (B_ * M_ * KNB)   // 131072

typedef unsigned short u16;
typedef __attribute__((ext_vector_type(4))) unsigned int u32x4;
typedef __attribute__((ext_vector_type(8))) short short8;
typedef __attribute__((ext_vector_type(4))) float f32x4v;

__device__ inline u16 f2bf(float f) {
  union { float f; unsigned u; } x; x.f = f;
  unsigned r = x.u + 0x7fffu + ((x.u >> 16) & 1u);
  return (u16)(r >> 16);
}
__device__ inline float bf2f(u16 h) {
  union { unsigned u; float f; } x; x.u = ((unsigned)h) << 16;
  return x.f;
}

// ---------------------------------------------------------------------------
// FPS (r3 structure: 1 barrier/iter; selection arithmetic bit-matched to the
// r1-verified chain).
// ---------------------------------------------------------------------------
__global__ __launch_bounds__(256) void fps_kernel(const float* __restrict__ x,
                                                  float* __restrict__ pts) {
  __shared__ float xs[N_ * 3];
  __shared__ float rv[2][4];
  __shared__ int   ri[2][4];
  const int b = blockIdx.x, t = threadIdx.x, lane = t & 63, w = t >> 6;
  const float* xb = x + (size_t)b * N_ * 3;
  for (int s = t; s < N_ * 3; s += 256) xs[s] = xb[s];
  __syncthreads();

  float px[16], py[16], pz[16], dm[16];
#pragma unroll
  for (int j = 0; j < 16; ++j) {
    int p = t + j * 256;
    px[j] = xs[p * 3 + 0]; py[j] = xs[p * 3 + 1]; pz[j] = xs[p * 3 + 2];
    dm[j] = __builtin_inff();
  }
  float cx = xs[0], cy = xs[1], cz = xs[2];
  if (t == 0) {
    pts[(size_t)b * M_ * 3 + 0] = cx;
    pts[(size_t)b * M_ * 3 + 1] = cy;
    pts[(size_t)b * M_ * 3 + 2] = cz;
  }
  for (int i = 1; i < M_; ++i) {
    float d[16];
#pragma unroll
    for (int j = 0; j < 16; ++j) {
      float dx = px[j] - cx, dy = py[j] - cy, dz = pz[j] - cz;
      float dd = __fmul_rn(dx, dx);
      dd = __fadd_rn(dd, __fmul_rn(dy, dy));
      dd = __fadd_rn(dd, __fmul_rn(dz, dz));
      dd = fminf(dm[j], dd);
      dm[j] = dd;
      d[j] = dd;
    }
    float v8[8]; int j8[8];
#pragma unroll
    for (int j = 0; j < 8; ++j) {
      bool tk = d[j + 8] > d[j];
      v8[j] = tk ? d[j + 8] : d[j];
      j8[j] = tk ? (j + 8) : j;
    }
    float v4[4]; int i4[4];
#pragma unroll
    for (int j = 0; j < 4; ++j) {
      bool tk = (v8[j + 4] > v8[j]) || (v8[j + 4] == v8[j] && j8[j + 4] < j8[j]);
      v4[j] = tk ? v8[j + 4] : v8[j];
      i4[j] = tk ? j8[j + 4] : j8[j];
    }
    float v2[2]; int i2[2];
#pragma unroll
    for (int j = 0; j < 2; ++j) {
      bool tk = (v4[j + 2] > v4[j]) || (v4[j + 2] == v4[j] && i4[j + 2] < i4[j]);
      v2[j] = tk ? v4[j + 2] : v4[j];
      i2[j] = tk ? i4[j + 2] : i4[j];
    }
    bool tk0 = (v2[1] > v2[0]) || (v2[1] == v2[0] && i2[1] < i2[0]);
    float bv = tk0 ? v2[1] : v2[0];
    int bi = t + (tk0 ? i2[1] : i2[0]) * 256;
#pragma unroll
    for (int off = 32; off >= 1; off >>= 1) {
      float ov = __shfl_xor(bv, off);
      int   oi = __shfl_xor(bi, off);
      if (ov > bv || (ov == bv && oi < bi)) { bv = ov; bi = oi; }
    }
    const int par = i & 1;
    if (lane == 0) { rv[par][w] = bv; ri[par][w] = bi; }
    __syncthreads();
    float fv = rv[par][0]; int fi = ri[par][0];
#pragma unroll
    for (int q = 1; q < 4; ++q) {
      float qv = rv[par][q]; int qi = ri[par][q];
      if (qv > fv || (qv == fv && qi < fi)) { fv = qv; fi = qi; }
    }
    cx = xs[fi * 3 + 0]; cy = xs[fi * 3 + 1]; cz = xs[fi * 3 + 2];
    if (t == 0) {
      pts[((size_t)b * M_ + i) * 3 + 0] = cx;
      pts[((size_t)b * M_ + i) * 3 + 1] = cy;
      pts[((size_t)b * M_ + i) * 3 + 2] = cz;
    }
  }
}

// ---------------------------------------------------------------------------
// kNN (unchanged, r1-verified)
// ---------------------------------------------------------------------------
template <int C>
__global__ __launch_bounds__(256) void knn_kernel(const float* __restrict__ f,
                                                  int* __restrict__ knn) {
  constexpr int C4 = (C + 3) / 4;
  __shared__ float4 ls4[C4 * 513];
  float* lss = (float*)ls4;
  const int b = blockIdx.x >> 4;
  const int mb = (blockIdx.x & 15) * 32;
  const int t = threadIdx.x, lane = t & 63, w = t >> 6;
  const float* fb = f + (size_t)b * M_ * C;
  if (C & 3) {
    for (int j = t; j < M_; j += 256)
      for (int cc = (C & 3); cc < 4; ++cc)
        lss[((C4 - 1) * 513 + j) * 4 + cc] = 0.f;
  }
  for (int s = t; s < M_ * C; s += 256) {
    int j = s / C, c = s % C;
    lss[((c >> 2) * 513 + j) * 4 + (c & 3)] = fb[s];
  }
  __syncthreads();

  float sqj[8];
#pragma unroll
  for (int jj = 0; jj < 8; ++jj) {
    int j = lane + 64 * jj;
    float a = 0.f;
    for (int c4 = 0; c4 < C4; ++c4) {
      float4 v = ls4[c4 * 513 + j];
      a += v.x * v.x + v.y * v.y + v.z * v.z + v.w * v.w;
    }
    sqj[jj] = a;
  }

  for (int rr = 0; rr < 8; ++rr) {
    const int m = mb + w * 8 + rr;
    float sqm = 0.f;
    for (int c4 = 0; c4 < C4; ++c4) {
      float4 v = ls4[c4 * 513 + m];
      sqm += v.x * v.x + v.y * v.y + v.z * v.z + v.w * v.w;
    }
    float dot[8] = {0.f, 0.f, 0.f, 0.f, 0.f, 0.f, 0.f, 0.f};
    for (int c4 = 0; c4 < C4; ++c4) {
      float4 fm = ls4[c4 * 513 + m];
#pragma unroll
      for (int jj = 0; jj < 8; ++jj) {
        float4 fj = ls4[c4 * 513 + lane + 64 * jj];
        dot[jj] += fm.x * fj.x + fm.y * fj.y + fm.z * fj.z + fm.w * fj.w;
      }
    }
    float d[8];
#pragma unroll
    for (int jj = 0; jj < 8; ++jj) d[jj] = (sqm - 2.f * dot[jj]) + sqj[jj];

    unsigned used = 0;
    int* out = knn + ((size_t)b * M_ + m) * KNB;
    for (int kk = 0; kk < KNB; ++kk) {
      float bv = __builtin_inff();
      int bi = 0x7fffffff;
#pragma unroll
      for (int jj = 0; jj < 8; ++jj) {
        if (!(used & (1u << jj))) {
          int j = lane + 64 * jj;
          if (d[jj] < bv || (d[jj] == bv && j < bi)) { bv = d[jj]; bi = j; }
        }
      }
#pragma unroll
      for (int off = 32; off >= 1; off >>= 1) {
        float ov = __shfl_xor(bv, off);
        int   oi = __shfl_xor(bi, off);
        if (ov < bv || (ov == bv && oi < bi)) { bv = ov; bi = oi; }
      }
      if ((bi & 63) == lane) used |= 1u << (bi >> 6);
      if (lane == 0) out[kk] = bi;
    }
  }
}

// ---------------------------------------------------------------------------
// Per-point projections, all-f32 output PC[p] = [ Pu | Cu | Pv | Cv ] (4D).
//   Pu = (Wq-Wk)_l f ; Cu = ((Wq-Wk)_r - (Wq-Wk)_l) f
//   Pv = Wv_l f      ; Cv = (Wv_r - Wv_l) f
// ---------------------------------------------------------------------------
__global__ __launch_bounds__(256) void pointproj_kernel(
    const float* __restrict__ f, const float* __restrict__ Wq,
    const float* __restrict__ Wk, const float* __restrict__ Wv,
    float* __restrict__ PC, int C, int D) {
  __shared__ float As[16][68];
  __shared__ float Ws[16][68];
  const int t = threadIdx.x;
  const int r0 = blockIdx.x * 64, n0 = blockIdx.y * 64;
  const int tr = t >> 4, tc = t & 15;
  const int twoC = 2 * C;
  const int fourD = 4 * D;
  float acc[4][4] = {};
  const int Ksteps = (C + 15) / 16;
  for (int ks = 0; ks < Ksteps; ++ks) {
    int k0 = ks * 16;
#pragma unroll
    for (int s = 0; s < 4; ++s) {
      int id = t + s * 256;
      int kk = id & 15, rr = id >> 4;
      int c = k0 + kk;
      As[kk][rr] = (c < C) ? f[(size_t)(r0 + rr) * C + c] : 0.f;
      float wv = 0.f;
      if (c < C) {
        int n = n0 + rr;
        int reg = n / D, d = n % D;
        if (reg == 0)      wv = Wq[d * twoC + c] - Wk[d * twoC + c];
        else if (reg == 1) wv = (Wq[d * twoC + C + c] - Wk[d * twoC + C + c]) -
                                (Wq[d * twoC + c] - Wk[d * twoC + c]);
        else if (reg == 2) wv = Wv[d * twoC + c];
        else               wv = Wv[d * twoC + C + c] - Wv[d * twoC + c];
      }
      Ws[kk][rr] = wv;
    }
    __syncthreads();
#pragma unroll
    for (int kk = 0; kk < 16; ++kk) {
      float4 a = *(const float4*)&As[kk][tr * 4];
      float4 bq = *(const float4*)&Ws[kk][tc * 4];
      acc[0][0] += a.x * bq.x; acc[0][1] += a.x * bq.y; acc[0][2] += a.x * bq.z; acc[0][3] += a.x * bq.w;
      acc[1][0] += a.y * bq.x; acc[1][1] += a.y * bq.y; acc[1][2] += a.y * bq.z; acc[1][3] += a.y * bq.w;
      acc[2][0] += a.z * bq.x; acc[2][1] += a.z * bq.y; acc[2][2] += a.z * bq.z; acc[2][3] += a.z * bq.w;
      acc[3][0] += a.w * bq.x; acc[3][1] += a.w * bq.y; acc[3][2] += a.w * bq.z; acc[3][3] += a.w * bq.w;
    }
    __syncthreads();
  }
  const int col = n0 + tc * 4;
#pragma unroll
  for (int i = 0; i < 4; ++i) {
    int row = r0 + tr * 4 + i;
    float4 o; o.x = acc[i][0]; o.y = acc[i][1]; o.z = acc[i][2]; o.w = acc[i][3];
    *(float4*)&PC[(size_t)row * fourD + col] = o;
  }
}

// ---------------------------------------------------------------------------
// Build per-row u (f32) and h1 = relu(P1 . rel) (f32). One thread per (row,d).
// ---------------------------------------------------------------------------
__global__ __launch_bounds__(256) void build_kernel(
    const float* __restrict__ pts, const float* __restrict__ P1,
    const float* __restrict__ PC, const int* __restrict__ idx,
    float* __restrict__ u, float* __restrict__ h1, int D, int dsh, int r0g) {
  int gid = blockIdx.x * 256 + threadIdx.x;
  int r = gid >> dsh, d = gid & (D - 1);
  int gr = r0g + r;
  int n = idx[gr];
  int bm = gr >> 4;
  int b = gr >> 13;
  int np = b * M_ + n;
  int fourD = 4 * D;
  u[(size_t)r * D + d] = PC[(size_t)np * fourD + d] + PC[(size_t)bm * fourD + D + d];
  float rx = pts[np * 3 + 0] - pts[bm * 3 + 0];
  float ry = pts[np * 3 + 1] - pts[bm * 3 + 1];
  float rz = pts[np * 3 + 2] - pts[bm * 3 + 2];
  float hh = P1[d * 3 + 0] * rx + P1[d * 3 + 1] * ry + P1[d * 3 + 2] * rz;
  h1[(size_t)r * D + d] = fmaxf(hh, 0.f);
}

// ---------------------------------------------------------------------------
// Split-precision MFMA GEMM: out = act( A(+A2p) @ W^T ), everything f32 in/out.
// Both operands decomposed hi+lo bf16; 3 MFMA products (hi*hi + lo*hi + hi*lo)
// -> ~fp32-grade result (dropped lo*lo <= 2^-18 relative).
// 64x64 tile, 4 waves x (32x32 via 2x2 16x16x32 fragments).
// ---------------------------------------------------------------------------
template <int RELU, int ADDF32>
__global__ __launch_bounds__(256) void gemm_split(
    const float* __restrict__ A, const float* __restrict__ A2p,
    const float* __restrict__ W, float* __restrict__ out, int N, int K) {
  __shared__ u32x4 Ah[4 * 65];
  __shared__ u32x4 Al[4 * 65];
  __shared__ u32x4 Wh[4 * 65];
  __shared__ u32x4 Wl[4 * 65];
  const int t = threadIdx.x;
  const int r0 = blockIdx.x * 64, n0 = blockIdx.y * 64;
  const int lane = t & 63, w = t >> 6;
  const int wr = (w >> 1) * 32, wc = (w & 1) * 32;
  f32x4v acc00 = {0.f, 0.f, 0.f, 0.f}, acc01 = acc00, acc10 = acc00, acc11 = acc00;
  const int srow = t >> 2, ss = t & 3;
  const size_t arow = (size_t)(r0 + srow) * K + ss * 8;
  const float* ga = A + arow;
  const float* gb = A2p + arow;
  const float* gw = W + (size_t)(n0 + srow) * K + ss * 8;
  const int ldsw = ss * 65 + srow;
  const int ra = (lane >> 4) * 65 + (lane & 15);

  for (int k0 = 0; k0 < K; k0 += 32) {
    float af[8], wf[8];
    *(float4*)&af[0] = *(const float4*)(ga + k0);
    *(float4*)&af[4] = *(const float4*)(ga + k0 + 4);
    if (ADDF32) {
      float4 b0 = *(const float4*)(gb + k0);
      float4 b1 = *(const float4*)(gb + k0 + 4);
      af[0] += b0.x; af[1] += b0.y; af[2] += b0.z; af[3] += b0.w;
      af[4] += b1.x; af[5] += b1.y; af[6] += b1.z; af[7] += b1.w;
    }
    *(float4*)&wf[0] = *(const float4*)(gw + k0);
    *(float4*)&wf[4] = *(const float4*)(gw + k0 + 4);
    u32x4 vah, val, vwh, vwl;
#pragma unroll
    for (int q = 0; q < 4; ++q) {
      u16 h0 = f2bf(af[2 * q]), h1 = f2bf(af[2 * q + 1]);
      u16 l0 = f2bf(af[2 * q] - bf2f(h0));
      u16 l1 = f2bf(af[2 * q + 1] - bf2f(h1));
      vah[q] = (unsigned)h0 | ((unsigned)h1 << 16);
      val[q] = (unsigned)l0 | ((unsigned)l1 << 16);
      u16 wh0 = f2bf(wf[2 * q]), wh1 = f2bf(wf[2 * q + 1]);
      u16 wl0 = f2bf(wf[2 * q] - bf2f(wh0));
      u16 wl1 = f2bf(wf[2 * q + 1] - bf2f(wh1));
      vwh[q] = (unsigned)wh0 | ((unsigned)wh1 << 16);
      vwl[q] = (unsigned)wl0 | ((unsigned)wl1 << 16);
    }
    __syncthreads();
    Ah[ldsw] = vah; Al[ldsw] = val;
    Wh[ldsw] = vwh; Wl[ldsw] = vwl;
    __syncthreads();
    union { u32x4 u; short8 s; } ah0, ah1, al0, al1, bh0, bh1, bl0, bl1;
    ah0.u = Ah[ra + wr]; ah1.u = Ah[ra + wr + 16];
    al0.u = Al[ra + wr]; al1.u = Al[ra + wr + 16];
    bh0.u = Wh[ra + wc]; bh1.u = Wh[ra + wc + 16];
    bl0.u = Wl[ra + wc]; bl1.u = Wl[ra + wc + 16];
    acc00 = __builtin_amdgcn_mfma_f32_16x16x32_bf16(ah0.s, bh0.s, acc00, 0, 0, 0);
    acc01 = __builtin_amdgcn_mfma_f32_16x16x32_bf16(ah0.s, bh1.s, acc01, 0, 0, 0);
    acc10 = __builtin_amdgcn_mfma_f32_16x16x32_bf16(ah1.s, bh0.s, acc10, 0, 0, 0);
    acc11 = __builtin_amdgcn_mfma_f32_16x16x32_bf16(ah1.s, bh1.s, acc11, 0, 0, 0);
    acc00 = __builtin_amdgcn_mfma_f32_16x16x32_bf16(al0.s, bh0.s, acc00, 0, 0, 0);
    acc01 = __builtin_amdgcn_mfma_f32_16x16x32_bf16(al0.s, bh1.s, acc01, 0, 0, 0);
    acc10 = __builtin_amdgcn_mfma_f32_16x16x32_bf16(al1.s, bh0.s, acc10, 0, 0, 0);
    acc11 = __builtin_amdgcn_mfma_f32_16x16x32_bf16(al1.s, bh1.s, acc11, 0, 0, 0);
    acc00 = __builtin_amdgcn_mfma_f32_16x16x32_bf16(ah0.s, bl0.s, acc00, 0, 0, 0);
    acc01 = __builtin_amdgcn_mfma_f32_16x16x32_bf16(ah0.s, bl1.s, acc01, 0, 0, 0);
    acc10 = __builtin_amdgcn_mfma_f32_16x16x32_bf16(ah1.s, bl0.s, acc10, 0, 0, 0);
    acc11 = __builtin_amdgcn_mfma_f32_16x16x32_bf16(ah1.s, bl1.s, acc11, 0, 0, 0);
  }

  const int rowb = r0 + wr + (lane >> 4) * 4;
  const int colb = n0 + wc + (lane & 15);
#pragma unroll
  for (int fr = 0; fr < 2; ++fr)
#pragma unroll
    for (int fc = 0; fc < 2; ++fc) {
      f32x4v ac = fr == 0 ? (fc == 0 ? acc00 : acc01) : (fc == 0 ? acc10 : acc11);
#pragma unroll
      for (int q = 0; q < 4; ++q) {
        float val = ac[q];
        if (RELU) val = fmaxf(val, 0.f);
        int row = rowb + fr * 16 + q;
        int col = colb + fc * 16;
        out[(size_t)row * N + col] = val;
      }
    }
}

// ---------------------------------------------------------------------------
// softmax over k=16; w = v + pe, v gathered f32 from PC via idx.
// ---------------------------------------------------------------------------
template <int DSH>
__global__ __launch_bounds__(256) void softmax_kernel(
    const float* __restrict__ logits, const float* __restrict__ pe,
    const float* __restrict__ PC, const int* __restrict__ idx,
    float* __restrict__ xout, int r0g) {
  const int D = 1 << DSH;
  const int fourD = 4 * D;
  const int pid = blockIdx.x * (256 >> DSH) + (threadIdx.x >> DSH);
  const int d = threadIdx.x & (D - 1);
  const size_t r0 = (size_t)pid * KNB;
  float l[KNB];
  float mx = -__builtin_inff();
#pragma unroll
  for (int k = 0; k < KNB; ++k) {
    l[k] = logits[(r0 + k) * D + d];
    mx = fmaxf(mx, l[k]);
  }
  float s = 0.f;
#pragma unroll
  for (int k = 0; k < KNB; ++k) {
    l[k] = expf(l[k] - mx);
    s += l[k];
  }
  const int gr0 = r0g + (int)r0;
  float acc = 0.f;
#pragma unroll
  for (int k = 0; k < KNB; ++k) {
    int gr = gr0 + k;
    int n = idx[gr];
    int bm = gr >> 4;
    int b = gr >> 13;
    int np = b * M_ + n;
    float vv = PC[(size_t)np * fourD + 2 * D + d] + PC[(size_t)bm * fourD + 3 * D + d];
    acc += l[k] * (vv + pe[(r0 + k) * D + d]);
  }
  xout[(size_t)(r0g / KNB + pid) * D + d] = acc / s;
}

// ---------------------------------------------------------------------------
__global__ __launch_bounds__(256) void final_kernel(const float* __restrict__ x1,
                                                    const float* __restrict__ x2,
                                                    const float* __restrict__ x3,
                                                    float* __restrict__ out) {
  const int b = blockIdx.x, c = threadIdx.x;
  const float* p;
  int D, dc;
  if (c < 64)        { p = x1 + (size_t)b * M_ * 64;  D = 64;  dc = c; }
  else if (c < 128)  { p = x2 + (size_t)b * M_ * 64;  D = 64;  dc = c - 64; }
  else               { p = x3 + (size_t)b * M_ * 128; D = 128; dc = c - 128; }
  float mx = -__builtin_inff(), sm = 0.f;
  for (int m = 0; m < M_; ++m) {
    float v = p[(size_t)m * D + dc];
    mx = fmaxf(mx, v);
    sm += v;
  }
  out[(size_t)b * 512 + c] = mx;
  out[(size_t)b * 512 + 256 + c] = sm * (1.f / 512.f);
}

// ---------------------------------------------------------------------------
extern "C" void kernel_launch(void* const* d_in, const int* in_sizes, int n_in,
                              void* d_out, int out_size, void* d_ws, size_t ws_size,
                              hipStream_t stream) {
  const float* x = (const float*)d_in[0];
  const float* W[21];
  for (int i = 0; i < 21; ++i) W[i] = (const float*)d_in[1 + i];

  float* ws = (float*)d_ws;
  size_t off = 0;
  auto alloc = [&](size_t nfloats) { float* p = ws + off; off += nfloats; return p; };

  // fixed buffers (25.8 MB)
  float* pts = alloc(24592);
  float* x1  = alloc((size_t)P_ * 64);
  float* x2  = alloc((size_t)P_ * 64);
  float* x3  = alloc((size_t)P_ * 128);
  int*   idxb = (int*)alloc((size_t)P_ * KNB);
  float* PC  = alloc((size_t)P_ * 512);   // [P][4D_max] f32 (Pu|Cu|Pv|Cv)

  // chunk scratch (sized for max over layers; 14.7 MB)
  float* ub  = alloc(524288);    // u f32 (and logits overlay after A1)
  float* peb = alloc(524288);    // pe f32
  float* h1b = alloc(524288);    // h1 f32
  float* hb  = alloc(2097152);   // h f32
  float* logb = ub;

  fps_kernel<<<B_, 256, 0, stream>>>(x, pts);

  struct Layer {
    const float* f; int C, D, dsh, H, RcRows;
    const float *Wq, *Wk, *Wv, *P1, *P2, *A1, *A2;
    float* xout;
  };
  Layer ls[3] = {
      {pts, 3, 64, 6, 256, 8192, W[0], W[1], W[2], W[3], W[4], W[5], W[6], x1},
      {x1, 64, 64, 6, 256, 8192, W[7], W[8], W[9], W[10], W[11], W[12], W[13], x2},
      {x2, 64, 128, 7, 512, 4096, W[14], W[15], W[16], W[17], W[18], W[19], W[20], x3},
  };

  for (int li = 0; li < 3; ++li) {
    const Layer& L = ls[li];
    if (L.C == 3) knn_kernel<3><<<B_ * 16, 256, 0, stream>>>(L.f, idxb);
    else          knn_kernel<64><<<B_ * 16, 256, 0, stream>>>(L.f, idxb);

    pointproj_kernel<<<dim3(P_ / 64, 4 * L.D / 64), 256, 0, stream>>>(
        L.f, L.Wq, L.Wk, L.Wv, PC, L.C, L.D);

    const int rows = L.RcRows;
    for (int r0g = 0; r0g < ROWS_; r0g += rows) {
      build_kernel<<<rows * L.D / 256, 256, 0, stream>>>(
          pts, L.P1, PC, idxb, ub, h1b, L.D, L.dsh, r0g);

      dim3 gP2(rows / 64, L.D / 64);
      gemm_split<0, 0><<<gP2, 256, 0, stream>>>(h1b, nullptr, L.P2, peb, L.D, L.D);

      dim3 gA1(rows / 64, L.H / 64);
      gemm_split<1, 1><<<gA1, 256, 0, stream>>>(ub, peb, L.A1, hb, L.H, L.D);

      dim3 gA2(rows / 64, L.D / 64);
      gemm_split<0, 0><<<gA2, 256, 0, stream>>>(hb, nullptr, L.A2, logb, L.D, L.H);

      if (L.dsh == 6)
        softmax_kernel<6><<<(rows / KNB) / 4, 256, 0, stream>>>(logb, peb, PC, idxb, L.xout, r0g);
      else
        softmax_kernel<7><<<(rows / KNB) / 2, 256, 0, stream>>>(logb, peb, PC, idxb, L.xout, r0g);
    }
  }

  final_kernel<<<B_, 256, 0, stream>>>(x1, x2, x3, (float*)d_out);
}

// Round 5
// 1860.504 us; speedup vs baseline: 1.8481x; 1.7993x over previous
//
#include <hip/hip_runtime.h>
#include <cstdint>
#include <cstddef>

#define B_  16
#define N_  4096
#define M_  512
#define KNB 16
#define P_  (B_ * M_)
#define ROWS_ (B_ * M_ * KNB)   // 131072

typedef unsigned short u16;
typedef __attribute__((ext_vector_type(4))) unsigned int u32x4;
typedef __attribute__((ext_vector_type(8))) short short8;
typedef __attribute__((ext_vector_type(4))) float f32x4v;

__device__ inline u16 f2bf(float f) {
  union { float f; unsigned u; } x; x.f = f;
  unsigned r = x.u + 0x7fffu + ((x.u >> 16) & 1u);
  return (u16)(r >> 16);
}
__device__ inline float bf2f(u16 h) {
  union { unsigned u; float f; } x; x.u = ((unsigned)h) << 16;
  return x.f;
}

// ---------------------------------------------------------------------------
// FPS (r4-verified)
// ---------------------------------------------------------------------------
__global__ __launch_bounds__(256) void fps_kernel(const float* __restrict__ x,
                                                  float* __restrict__ pts) {
  __shared__ float xs[N_ * 3];
  __shared__ float rv[2][4];
  __shared__ int   ri[2][4];
  const int b = blockIdx.x, t = threadIdx.x, lane = t & 63, w = t >> 6;
  const float* xb = x + (size_t)b * N_ * 3;
  for (int s = t; s < N_ * 3; s += 256) xs[s] = xb[s];
  __syncthreads();

  float px[16], py[16], pz[16], dm[16];
#pragma unroll
  for (int j = 0; j < 16; ++j) {
    int p = t + j * 256;
    px[j] = xs[p * 3 + 0]; py[j] = xs[p * 3 + 1]; pz[j] = xs[p * 3 + 2];
    dm[j] = __builtin_inff();
  }
  float cx = xs[0], cy = xs[1], cz = xs[2];
  if (t == 0) {
    pts[(size_t)b * M_ * 3 + 0] = cx;
    pts[(size_t)b * M_ * 3 + 1] = cy;
    pts[(size_t)b * M_ * 3 + 2] = cz;
  }
  for (int i = 1; i < M_; ++i) {
    float d[16];
#pragma unroll
    for (int j = 0; j < 16; ++j) {
      float dx = px[j] - cx, dy = py[j] - cy, dz = pz[j] - cz;
      float dd = __fmul_rn(dx, dx);
      dd = __fadd_rn(dd, __fmul_rn(dy, dy));
      dd = __fadd_rn(dd, __fmul_rn(dz, dz));
      dd = fminf(dm[j], dd);
      dm[j] = dd;
      d[j] = dd;
    }
    float v8[8]; int j8[8];
#pragma unroll
    for (int j = 0; j < 8; ++j) {
      bool tk = d[j + 8] > d[j];
      v8[j] = tk ? d[j + 8] : d[j];
      j8[j] = tk ? (j + 8) : j;
    }
    float v4[4]; int i4[4];
#pragma unroll
    for (int j = 0; j < 4; ++j) {
      bool tk = (v8[j + 4] > v8[j]) || (v8[j + 4] == v8[j] && j8[j + 4] < j8[j]);
      v4[j] = tk ? v8[j + 4] : v8[j];
      i4[j] = tk ? j8[j + 4] : j8[j];
    }
    float v2[2]; int i2[2];
#pragma unroll
    for (int j = 0; j < 2; ++j) {
      bool tk = (v4[j + 2] > v4[j]) || (v4[j + 2] == v4[j] && i4[j + 2] < i4[j]);
      v2[j] = tk ? v4[j + 2] : v4[j];
      i2[j] = tk ? i4[j + 2] : i4[j];
    }
    bool tk0 = (v2[1] > v2[0]) || (v2[1] == v2[0] && i2[1] < i2[0]);
    float bv = tk0 ? v2[1] : v2[0];
    int bi = t + (tk0 ? i2[1] : i2[0]) * 256;
#pragma unroll
    for (int off = 32; off >= 1; off >>= 1) {
      float ov = __shfl_xor(bv, off);
      int   oi = __shfl_xor(bi, off);
      if (ov > bv || (ov == bv && oi < bi)) { bv = ov; bi = oi; }
    }
    const int par = i & 1;
    if (lane == 0) { rv[par][w] = bv; ri[par][w] = bi; }
    __syncthreads();
    float fv = rv[par][0]; int fi = ri[par][0];
#pragma unroll
    for (int q = 1; q < 4; ++q) {
      float qv = rv[par][q]; int qi = ri[par][q];
      if (qv > fv || (qv == fv && qi < fi)) { fv = qv; fi = qi; }
    }
    cx = xs[fi * 3 + 0]; cy = xs[fi * 3 + 1]; cz = xs[fi * 3 + 2];
    if (t == 0) {
      pts[((size_t)b * M_ + i) * 3 + 0] = cx;
      pts[((size_t)b * M_ + i) * 3 + 1] = cy;
      pts[((size_t)b * M_ + i) * 3 + 2] = cz;
    }
  }
}

// ---------------------------------------------------------------------------
// kNN (r1-verified)
// ---------------------------------------------------------------------------
template <int C>
__global__ __launch_bounds__(256) void knn_kernel(const float* __restrict__ f,
                                                  int* __restrict__ knn) {
  constexpr int C4 = (C + 3) / 4;
  __shared__ float4 ls4[C4 * 513];
  float* lss = (float*)ls4;
  const int b = blockIdx.x >> 4;
  const int mb = (blockIdx.x & 15) * 32;
  const int t = threadIdx.x, lane = t & 63, w = t >> 6;
  const float* fb = f + (size_t)b * M_ * C;
  if (C & 3) {
    for (int j = t; j < M_; j += 256)
      for (int cc = (C & 3); cc < 4; ++cc)
        lss[((C4 - 1) * 513 + j) * 4 + cc] = 0.f;
  }
  for (int s = t; s < M_ * C; s += 256) {
    int j = s / C, c = s % C;
    lss[((c >> 2) * 513 + j) * 4 + (c & 3)] = fb[s];
  }
  __syncthreads();

  float sqj[8];
#pragma unroll
  for (int jj = 0; jj < 8; ++jj) {
    int j = lane + 64 * jj;
    float a = 0.f;
    for (int c4 = 0; c4 < C4; ++c4) {
      float4 v = ls4[c4 * 513 + j];
      a += v.x * v.x + v.y * v.y + v.z * v.z + v.w * v.w;
    }
    sqj[jj] = a;
  }

  for (int rr = 0; rr < 8; ++rr) {
    const int m = mb + w * 8 + rr;
    float sqm = 0.f;
    for (int c4 = 0; c4 < C4; ++c4) {
      float4 v = ls4[c4 * 513 + m];
      sqm += v.x * v.x + v.y * v.y + v.z * v.z + v.w * v.w;
    }
    float dot[8] = {0.f, 0.f, 0.f, 0.f, 0.f, 0.f, 0.f, 0.f};
    for (int c4 = 0; c4 < C4; ++c4) {
      float4 fm = ls4[c4 * 513 + m];
#pragma unroll
      for (int jj = 0; jj < 8; ++jj) {
        float4 fj = ls4[c4 * 513 + lane + 64 * jj];
        dot[jj] += fm.x * fj.x + fm.y * fj.y + fm.z * fj.z + fm.w * fj.w;
      }
    }
    float d[8];
#pragma unroll
    for (int jj = 0; jj < 8; ++jj) d[jj] = (sqm - 2.f * dot[jj]) + sqj[jj];

    unsigned used = 0;
    int* out = knn + ((size_t)b * M_ + m) * KNB;
    for (int kk = 0; kk < KNB; ++kk) {
      float bv = __builtin_inff();
      int bi = 0x7fffffff;
#pragma unroll
      for (int jj = 0; jj < 8; ++jj) {
        if (!(used & (1u << jj))) {
          int j = lane + 64 * jj;
          if (d[jj] < bv || (d[jj] == bv && j < bi)) { bv = d[jj]; bi = j; }
        }
      }
#pragma unroll
      for (int off = 32; off >= 1; off >>= 1) {
        float ov = __shfl_xor(bv, off);
        int   oi = __shfl_xor(bi, off);
        if (ov < bv || (ov == bv && oi < bi)) { bv = ov; bi = oi; }
      }
      if ((bi & 63) == lane) used |= 1u << (bi >> 6);
      if (lane == 0) out[kk] = bi;
    }
  }
}

// ---------------------------------------------------------------------------
// Per-point projections, f32 (r4-verified): PC[p] = [ Pu | Cu | Pv | Cv ]
// ---------------------------------------------------------------------------
__global__ __launch_bounds__(256) void pointproj_kernel(
    const float* __restrict__ f, const float* __restrict__ Wq,
    const float* __restrict__ Wk, const float* __restrict__ Wv,
    float* __restrict__ PC, int C, int D) {
  __shared__ float As[16][68];
  __shared__ float Ws[16][68];
  const int t = threadIdx.x;
  const int r0 = blockIdx.x * 64, n0 = blockIdx.y * 64;
  const int tr = t >> 4, tc = t & 15;
  const int twoC = 2 * C;
  const int fourD = 4 * D;
  float acc[4][4] = {};
  const int Ksteps = (C + 15) / 16;
  for (int ks = 0; ks < Ksteps; ++ks) {
    int k0 = ks * 16;
#pragma unroll
    for (int s = 0; s < 4; ++s) {
      int id = t + s * 256;
      int kk = id & 15, rr = id >> 4;
      int c = k0 + kk;
      As[kk][rr] = (c < C) ? f[(size_t)(r0 + rr) * C + c] : 0.f;
      float wv = 0.f;
      if (c < C) {
        int n = n0 + rr;
        int reg = n / D, d = n % D;
        if (reg == 0)      wv = Wq[d * twoC + c] - Wk[d * twoC + c];
        else if (reg == 1) wv = (Wq[d * twoC + C + c] - Wk[d * twoC + C + c]) -
                                (Wq[d * twoC + c] - Wk[d * twoC + c]);
        else if (reg == 2) wv = Wv[d * twoC + c];
        else               wv = Wv[d * twoC + C + c] - Wv[d * twoC + c];
      }
      Ws[kk][rr] = wv;
    }
    __syncthreads();
#pragma unroll
    for (int kk = 0; kk < 16; ++kk) {
      float4 a = *(const float4*)&As[kk][tr * 4];
      float4 bq = *(const float4*)&Ws[kk][tc * 4];
      acc[0][0] += a.x * bq.x; acc[0][1] += a.x * bq.y; acc[0][2] += a.x * bq.z; acc[0][3] += a.x * bq.w;
      acc[1][0] += a.y * bq.x; acc[1][1] += a.y * bq.y; acc[1][2] += a.y * bq.z; acc[1][3] += a.y * bq.w;
      acc[2][0] += a.z * bq.x; acc[2][1] += a.z * bq.y; acc[2][2] += a.z * bq.z; acc[2][3] += a.z * bq.w;
      acc[3][0] += a.w * bq.x; acc[3][1] += a.w * bq.y; acc[3][2] += a.w * bq.z; acc[3][3] += a.w * bq.w;
    }
    __syncthreads();
  }
  const int col = n0 + tc * 4;
#pragma unroll
  for (int i = 0; i < 4; ++i) {
    int row = r0 + tr * 4 + i;
    float4 o; o.x = acc[i][0]; o.y = acc[i][1]; o.z = acc[i][2]; o.w = acc[i][3];
    *(float4*)&PC[(size_t)row * fourD + col] = o;
  }
}

// ---------------------------------------------------------------------------
// Weight split: f32 -> bf16 hi + bf16 lo (once per layer)
// ---------------------------------------------------------------------------
__global__ void split_w(const float* __restrict__ W, u16* __restrict__ Wh,
                        u16* __restrict__ Wl, int n) {
  int i = blockIdx.x * 256 + threadIdx.x;
  if (i < n) {
    float v = W[i];
    u16 h = f2bf(v);
    Wh[i] = h;
    Wl[i] = f2bf(v - bf2f(h));
  }
}

// ---------------------------------------------------------------------------
// Fused transformer layer. Block = 256 threads (4 waves), RB rows.
// Phases: build(u,h1) -> pe = h1@P2^T -> s = u+pe -> loop H tiles
// { a = relu(s@A1t^T); logits += a@A2t^T } -> softmax_k -> x out.
// All operands: bf16 hi/lo 3-term MFMA (fp32-grade). W frags direct from global.
// ---------------------------------------------------------------------------
template <int D, int H, int RB>
__global__ __launch_bounds__(256) void mega_kernel(
    const float* __restrict__ pts, const float* __restrict__ PC,
    const int* __restrict__ idx, const float* __restrict__ P1,
    const u16* __restrict__ P2h, const u16* __restrict__ P2l,
    const u16* __restrict__ A1h, const u16* __restrict__ A1l,
    const u16* __restrict__ A2h, const u16* __restrict__ A2l,
    float* __restrict__ xout) {
  constexpr int WC = D / 32;                 // wave cols over RBxD grid
  constexpr int HT = (RB == 64) ? 64 : 128;  // a-tile width
  constexpr int WCa = HT / 32;
  constexpr int KCD = D / 8;                 // u32x4 k-chunks (K=D); == HT/8
  constexpr int NIT = H / HT;
  constexpr int LSTR = RB + 1;
  constexpr int FD = 4 * D;

  __shared__ u32x4 sh_[KCD * LSTR], sl_[KCD * LSTR];   // s hi/lo
  __shared__ u32x4 xh_[KCD * LSTR], xl_[KCD * LSTR];   // h1, then a
  __shared__ float upe[RB][D];                          // u, then pe
  __shared__ float rel4[RB][4];
  __shared__ int   nps[RB];
  __shared__ float P1s[D][4];

  const int t = threadIdx.x, lane = t & 63, w = t >> 6;
  const int kch = lane >> 4, lrow = lane & 15;
  const int r0g = blockIdx.x * RB;
  const int bm0 = r0g >> 4;

  // phase 0: rel, np, P1
  if (t < RB) {
    int gr = r0g + t;
    int bb = gr >> 13;
    int np = bb * M_ + idx[gr];
    int bm = gr >> 4;
    nps[t] = np;
    rel4[t][0] = pts[np * 3 + 0] - pts[bm * 3 + 0];
    rel4[t][1] = pts[np * 3 + 1] - pts[bm * 3 + 1];
    rel4[t][2] = pts[np * 3 + 2] - pts[bm * 3 + 2];
  }
  for (int e = t; e < D * 4; e += 256) {
    int dd = e >> 2, c = e & 3;
    P1s[dd][c] = (c < 3) ? P1[dd * 3 + c] : 0.f;
  }
  __syncthreads();

  u16* xh_u = (u16*)xh_;
  u16* xl_u = (u16*)xl_;
  u16* sh_u = (u16*)sh_;
  u16* sl_u = (u16*)sl_;

  // phase 1: u (f32 LDS) + h1 (hi/lo LDS)
#pragma unroll
  for (int i = 0; i < RB * D / 256; ++i) {
    int e = t + i * 256;
    int r = e / D, dd = e % D;
    int bm = bm0 + (r >> 4);
    int np = nps[r];
    upe[r][dd] = PC[(size_t)np * FD + dd] + PC[(size_t)bm * FD + D + dd];
    float hh = fmaxf(P1s[dd][0] * rel4[r][0] + P1s[dd][1] * rel4[r][1] +
                     P1s[dd][2] * rel4[r][2], 0.f);
    u16 hi = f2bf(hh), lo = f2bf(hh - bf2f(hi));
    int off = ((dd >> 3) * LSTR + r) * 8 + (dd & 7);
    xh_u[off] = hi; xl_u[off] = lo;
  }
  __syncthreads();

  const int wr2 = (w / WC) * 32, wc2 = (w % WC) * 32;

  // phase 2: pe = h1 @ P2^T ; s = u + pe ; upe <- pe
  {
    f32x4v pac[2][2];
#pragma unroll
    for (int a = 0; a < 2; ++a)
#pragma unroll
      for (int b = 0; b < 2; ++b) pac[a][b] = (f32x4v){0.f, 0.f, 0.f, 0.f};
#pragma unroll
    for (int k0 = 0; k0 < D; k0 += 32) {
      union { u32x4 u; short8 s; } ah[2], al[2], bh[2], bl[2];
#pragma unroll
      for (int fr = 0; fr < 2; ++fr) {
        int ai = ((k0 >> 3) + kch) * LSTR + wr2 + fr * 16 + lrow;
        ah[fr].u = xh_[ai]; al[fr].u = xl_[ai];
      }
#pragma unroll
      for (int fc = 0; fc < 2; ++fc) {
        size_t bi = (size_t)(wc2 + fc * 16 + lrow) * D + k0 + kch * 8;
        bh[fc].u = *(const u32x4*)(P2h + bi);
        bl[fc].u = *(const u32x4*)(P2l + bi);
      }
#pragma unroll
      for (int fr = 0; fr < 2; ++fr)
#pragma unroll
        for (int fc = 0; fc < 2; ++fc) {
          pac[fr][fc] = __builtin_amdgcn_mfma_f32_16x16x32_bf16(ah[fr].s, bh[fc].s, pac[fr][fc], 0, 0, 0);
          pac[fr][fc] = __builtin_amdgcn_mfma_f32_16x16x32_bf16(al[fr].s, bh[fc].s, pac[fr][fc], 0, 0, 0);
          pac[fr][fc] = __builtin_amdgcn_mfma_f32_16x16x32_bf16(ah[fr].s, bl[fc].s, pac[fr][fc], 0, 0, 0);
        }
    }
#pragma unroll
    for (int fr = 0; fr < 2; ++fr)
#pragma unroll
      for (int fc = 0; fc < 2; ++fc)
#pragma unroll
        for (int q = 0; q < 4; ++q) {
          int row = wr2 + fr * 16 + kch * 4 + q;
          int col = wc2 + fc * 16 + lrow;
          float pe = pac[fr][fc][q];
          float sv = pe + upe[row][col];
          upe[row][col] = pe;
          u16 hi = f2bf(sv), lo = f2bf(sv - bf2f(hi));
          int off = ((col >> 3) * LSTR + row) * 8 + (col & 7);
          sh_u[off] = hi; sl_u[off] = lo;
        }
  }
  __syncthreads();

  // phase 3: stream H tiles: a = relu(s @ A1t^T); logits += a @ A2t^T
  const int wra = (w / WCa) * 32, wca = (w % WCa) * 32;
  f32x4v lac[2][2];
#pragma unroll
  for (int a = 0; a < 2; ++a)
#pragma unroll
    for (int b = 0; b < 2; ++b) lac[a][b] = (f32x4v){0.f, 0.f, 0.f, 0.f};

#pragma unroll 1
  for (int it = 0; it < NIT; ++it) {
    const int hbase = it * HT;
    f32x4v aac[2][2];
#pragma unroll
    for (int a = 0; a < 2; ++a)
#pragma unroll
      for (int b = 0; b < 2; ++b) aac[a][b] = (f32x4v){0.f, 0.f, 0.f, 0.f};
#pragma unroll
    for (int k0 = 0; k0 < D; k0 += 32) {
      union { u32x4 u; short8 s; } ah[2], al[2], bh[2], bl[2];
#pragma unroll
      for (int fr = 0; fr < 2; ++fr) {
        int ai = ((k0 >> 3) + kch) * LSTR + wra + fr * 16 + lrow;
        ah[fr].u = sh_[ai]; al[fr].u = sl_[ai];
      }
#pragma unroll
      for (int fc = 0; fc < 2; ++fc) {
        size_t bi = (size_t)(hbase + wca + fc * 16 + lrow) * D + k0 + kch * 8;
        bh[fc].u = *(const u32x4*)(A1h + bi);
        bl[fc].u = *(const u32x4*)(A1l + bi);
      }
#pragma unroll
      for (int fr = 0; fr < 2; ++fr)
#pragma unroll
        for (int fc = 0; fc < 2; ++fc) {
          aac[fr][fc] = __builtin_amdgcn_mfma_f32_16x16x32_bf16(ah[fr].s, bh[fc].s, aac[fr][fc], 0, 0, 0);
          aac[fr][fc] = __builtin_amdgcn_mfma_f32_16x16x32_bf16(al[fr].s, bh[fc].s, aac[fr][fc], 0, 0, 0);
          aac[fr][fc] = __builtin_amdgcn_mfma_f32_16x16x32_bf16(ah[fr].s, bl[fc].s, aac[fr][fc], 0, 0, 0);
        }
    }
    __syncthreads();   // all waves done reading xh_ (prev a / h1)
#pragma unroll
    for (int fr = 0; fr < 2; ++fr)
#pragma unroll
      for (int fc = 0; fc < 2; ++fc)
#pragma unroll
        for (int q = 0; q < 4; ++q) {
          int row = wra + fr * 16 + kch * 4 + q;
          int ch = wca + fc * 16 + lrow;
          float av = fmaxf(aac[fr][fc][q], 0.f);
          u16 hi = f2bf(av), lo = f2bf(av - bf2f(hi));
          int off = ((ch >> 3) * LSTR + row) * 8 + (ch & 7);
          xh_u[off] = hi; xl_u[off] = lo;
        }
    __syncthreads();
#pragma unroll
    for (int k0 = 0; k0 < HT; k0 += 32) {
      union { u32x4 u; short8 s; } ah[2], al[2], bh[2], bl[2];
#pragma unroll
      for (int fr = 0; fr < 2; ++fr) {
        int ai = ((k0 >> 3) + kch) * LSTR + wr2 + fr * 16 + lrow;
        ah[fr].u = xh_[ai]; al[fr].u = xl_[ai];
      }
#pragma unroll
      for (int fc = 0; fc < 2; ++fc) {
        size_t bi = (size_t)(wc2 + fc * 16 + lrow) * H + hbase + k0 + kch * 8;
        bh[fc].u = *(const u32x4*)(A2h + bi);
        bl[fc].u = *(const u32x4*)(A2l + bi);
      }
#pragma unroll
      for (int fr = 0; fr < 2; ++fr)
#pragma unroll
        for (int fc = 0; fc < 2; ++fc) {
          lac[fr][fc] = __builtin_amdgcn_mfma_f32_16x16x32_bf16(ah[fr].s, bh[fc].s, lac[fr][fc], 0, 0, 0);
          lac[fr][fc] = __builtin_amdgcn_mfma_f32_16x16x32_bf16(al[fr].s, bh[fc].s, lac[fr][fc], 0, 0, 0);
          lac[fr][fc] = __builtin_amdgcn_mfma_f32_16x16x32_bf16(ah[fr].s, bl[fc].s, lac[fr][fc], 0, 0, 0);
        }
    }
  }

  // phase 4: softmax over k=16 (rows of a group) + output
#pragma unroll
  for (int fr = 0; fr < 2; ++fr) {
    const int bmg = bm0 + ((wr2 + fr * 16) >> 4);
#pragma unroll
    for (int fc = 0; fc < 2; ++fc) {
      const int col = wc2 + fc * 16 + lrow;
      float lv[4];
#pragma unroll
      for (int q = 0; q < 4; ++q) lv[q] = lac[fr][fc][q];
      float mx = fmaxf(fmaxf(lv[0], lv[1]), fmaxf(lv[2], lv[3]));
      mx = fmaxf(mx, __shfl_xor(mx, 16));
      mx = fmaxf(mx, __shfl_xor(mx, 32));
      float ev[4];
      float ssum = 0.f;
#pragma unroll
      for (int q = 0; q < 4; ++q) { ev[q] = expf(lv[q] - mx); ssum += ev[q]; }
      ssum += __shfl_xor(ssum, 16);
      ssum += __shfl_xor(ssum, 32);
      float acc = 0.f;
#pragma unroll
      for (int q = 0; q < 4; ++q) {
        int row = wr2 + fr * 16 + kch * 4 + q;
        int np = nps[row];
        float vv = PC[(size_t)np * FD + 2 * D + col] + PC[(size_t)bmg * FD + 3 * D + col];
        acc += ev[q] * (vv + upe[row][col]);
      }
      acc += __shfl_xor(acc, 16);
      acc += __shfl_xor(acc, 32);
      if (kch == 0) xout[(size_t)bmg * D + col] = acc / ssum;
    }
  }
}

// ---------------------------------------------------------------------------
__global__ __launch_bounds__(256) void final_kernel(const float* __restrict__ x1,
                                                    const float* __restrict__ x2,
                                                    const float* __restrict__ x3,
                                                    float* __restrict__ out) {
  const int b = blockIdx.x, c = threadIdx.x;
  const float* p;
  int D, dc;
  if (c < 64)        { p = x1 + (size_t)b * M_ * 64;  D = 64;  dc = c; }
  else if (c < 128)  { p = x2 + (size_t)b * M_ * 64;  D = 64;  dc = c - 64; }
  else               { p = x3 + (size_t)b * M_ * 128; D = 128; dc = c - 128; }
  float mx = -__builtin_inff(), sm = 0.f;
  for (int m = 0; m < M_; ++m) {
    float v = p[(size_t)m * D + dc];
    mx = fmaxf(mx, v);
    sm += v;
  }
  out[(size_t)b * 512 + c] = mx;
  out[(size_t)b * 512 + 256 + c] = sm * (1.f / 512.f);
}

// ---------------------------------------------------------------------------
extern "C" void kernel_launch(void* const* d_in, const int* in_sizes, int n_in,
                              void* d_out, int out_size, void* d_ws, size_t ws_size,
                              hipStream_t stream) {
  const float* x = (const float*)d_in[0];
  const float* W[21];
  for (int i = 0; i < 21; ++i) W[i] = (const float*)d_in[1 + i];

  float* ws = (float*)d_ws;
  size_t off = 0;
  auto alloc = [&](size_t nfloats) { float* p = ws + off; off += nfloats; return p; };

  float* pts = alloc(24592);
  float* x1  = alloc((size_t)P_ * 64);
  float* x2  = alloc((size_t)P_ * 64);
  float* x3  = alloc((size_t)P_ * 128);
  int*   idxb = (int*)alloc((size_t)P_ * KNB);
  float* PC  = alloc((size_t)P_ * 512);    // [P][4D_max] f32
  u16* P2h = (u16*)alloc(8192);   u16* P2l = (u16*)alloc(8192);
  u16* A1h = (u16*)alloc(32768);  u16* A1l = (u16*)alloc(32768);
  u16* A2h = (u16*)alloc(32768);  u16* A2l = (u16*)alloc(32768);

  fps_kernel<<<B_, 256, 0, stream>>>(x, pts);

  struct Layer {
    const float* f; int C, D, H;
    const float *Wq, *Wk, *Wv, *P1, *P2, *A1, *A2;
    float* xout;
  };
  Layer ls[3] = {
      {pts, 3, 64, 256, W[0], W[1], W[2], W[3], W[4], W[5], W[6], x1},
      {x1, 64, 64, 256, W[7], W[8], W[9], W[10], W[11], W[12], W[13], x2},
      {x2, 64, 128, 512, W[14], W[15], W[16], W[17], W[18], W[19], W[20], x3},
  };

  for (int li = 0; li < 3; ++li) {
    const Layer& L = ls[li];
    if (L.C == 3) knn_kernel<3><<<B_ * 16, 256, 0, stream>>>(L.f, idxb);
    else          knn_kernel<64><<<B_ * 16, 256, 0, stream>>>(L.f, idxb);

    pointproj_kernel<<<dim3(P_ / 64, 4 * L.D / 64), 256, 0, stream>>>(
        L.f, L.Wq, L.Wk, L.Wv, PC, L.C, L.D);

    int nP2 = L.D * L.D, nA1 = L.H * L.D, nA2 = L.D * L.H;
    split_w<<<(nP2 + 255) / 256, 256, 0, stream>>>(L.P2, P2h, P2l, nP2);
    split_w<<<(nA1 + 255) / 256, 256, 0, stream>>>(L.A1, A1h, A1l, nA1);
    split_w<<<(nA2 + 255) / 256, 256, 0, stream>>>(L.A2, A2h, A2l, nA2);

    if (L.D == 64)
      mega_kernel<64, 256, 64><<<ROWS_ / 64, 256, 0, stream>>>(
          pts, PC, idxb, L.P1, P2h, P2l, A1h, A1l, A2h, A2l, L.xout);
    else
      mega_kernel<128, 512, 32><<<ROWS_ / 32, 256, 0, stream>>>(
          pts, PC, idxb, L.P1, P2h, P2l, A1h, A1l, A2h, A2l, L.xout);
  }

  final_kernel<<<B_, 256, 0, stream>>>(x1, x2, x3, (float*)d_out);
}

// Round 6
// 1436.682 us; speedup vs baseline: 2.3933x; 1.2950x over previous
//
#include <hip/hip_runtime.h>
#include <cstdint>
#include <cstddef>

#define B_  16
#define N_  4096
#define M_  512
#define KNB 16
#define P_  (B_ * M_)
#define ROWS_ (B_ * M_ * KNB)   // 131072

typedef unsigned short u16;
typedef __attribute__((ext_vector_type(4))) unsigned int u32x4;
typedef __attribute__((ext_vector_type(8))) short short8;
typedef __attribute__((ext_vector_type(4))) float f32x4v;

__device__ inline u16 f2bf(float f) {
  union { float f; unsigned u; } x; x.f = f;
  unsigned r = x.u + 0x7fffu + ((x.u >> 16) & 1u);
  return (u16)(r >> 16);
}
__device__ inline float bf2f(u16 h) {
  union { unsigned u; float f; } x; x.u = ((unsigned)h) << 16;
  return x.f;
}

// ---------------------------------------------------------------------------
// DPP wave-64 reductions (row_shr 1/2/4/8 + row_bcast 15/31; result in lane 63,
// broadcast via readlane). ALU-latency instead of ds-routed shuffles.
// ---------------------------------------------------------------------------
__device__ inline float wave_max_f32(float m) {
#define STEPMAX(ctrl) m = fmaxf(m, __int_as_float(__builtin_amdgcn_update_dpp((int)0xff800000u, __float_as_int(m), ctrl, 0xf, 0xf, false)))
  STEPMAX(0x111); STEPMAX(0x112); STEPMAX(0x114); STEPMAX(0x118);
  STEPMAX(0x142); STEPMAX(0x143);
#undef STEPMAX
  return __int_as_float(__builtin_amdgcn_readlane(__float_as_int(m), 63));
}
__device__ inline float wave_min_f32(float m) {
#define STEPMINF(ctrl) m = fminf(m, __int_as_float(__builtin_amdgcn_update_dpp((int)0x7f800000, __float_as_int(m), ctrl, 0xf, 0xf, false)))
  STEPMINF(0x111); STEPMINF(0x112); STEPMINF(0x114); STEPMINF(0x118);
  STEPMINF(0x142); STEPMINF(0x143);
#undef STEPMINF
  return __int_as_float(__builtin_amdgcn_readlane(__float_as_int(m), 63));
}
__device__ inline unsigned wave_min_u32(unsigned m) {
#define STEPMINU(ctrl) { unsigned t_ = (unsigned)__builtin_amdgcn_update_dpp(-1, (int)m, ctrl, 0xf, 0xf, false); m = t_ < m ? t_ : m; }
  STEPMINU(0x111); STEPMINU(0x112); STEPMINU(0x114); STEPMINU(0x118);
  STEPMINU(0x142); STEPMINU(0x143);
#undef STEPMINU
  return (unsigned)__builtin_amdgcn_readlane((int)m, 63);
}

// ---------------------------------------------------------------------------
// FPS: 512 threads, 8 pts/lane, in-lane tree argmax (tie -> lowest index),
// DPP wave argmax, one barrier/iter (parity slots). Distance arithmetic
// bit-identical to the r4-verified chain; tie semantics = numpy argmax.
// ---------------------------------------------------------------------------
__global__ __launch_bounds__(512) void fps_kernel(const float* __restrict__ x,
                                                  float* __restrict__ pts) {
  __shared__ float xs[N_ * 3];
  __shared__ float rv[2][8];
  __shared__ int   ri[2][8];
  const int b = blockIdx.x, t = threadIdx.x, lane = t & 63, w = t >> 6;
  const float* xb = x + (size_t)b * N_ * 3;
  for (int s = t; s < N_ * 3; s += 512) xs[s] = xb[s];
  __syncthreads();

  float px[8], py[8], pz[8], dm[8];
#pragma unroll
  for (int j = 0; j < 8; ++j) {
    int p = t + j * 512;
    px[j] = xs[p * 3 + 0]; py[j] = xs[p * 3 + 1]; pz[j] = xs[p * 3 + 2];
    dm[j] = __builtin_inff();
  }
  float cx = xs[0], cy = xs[1], cz = xs[2];
  if (t == 0) {
    pts[(size_t)b * M_ * 3 + 0] = cx;
    pts[(size_t)b * M_ * 3 + 1] = cy;
    pts[(size_t)b * M_ * 3 + 2] = cz;
  }
  for (int i = 1; i < M_; ++i) {
    float d[8];
#pragma unroll
    for (int j = 0; j < 8; ++j) {
      float dx = px[j] - cx, dy = py[j] - cy, dz = pz[j] - cz;
      float dd = __fmul_rn(dx, dx);
      dd = __fadd_rn(dd, __fmul_rn(dy, dy));
      dd = __fadd_rn(dd, __fmul_rn(dz, dz));
      dd = fminf(dm[j], dd);
      dm[j] = dd;
      d[j] = dd;
    }
    float v4[4]; int j4[4];
#pragma unroll
    for (int j = 0; j < 4; ++j) {
      bool tk = d[j + 4] > d[j];
      v4[j] = tk ? d[j + 4] : d[j];
      j4[j] = tk ? (j + 4) : j;
    }
    float v2[2]; int j2[2];
#pragma unroll
    for (int j = 0; j < 2; ++j) {
      bool tk = (v4[j + 2] > v4[j]) || (v4[j + 2] == v4[j] && j4[j + 2] < j4[j]);
      v2[j] = tk ? v4[j + 2] : v4[j];
      j2[j] = tk ? j4[j + 2] : j4[j];
    }
    bool tk0 = (v2[1] > v2[0]) || (v2[1] == v2[0] && j2[1] < j2[0]);
    float bv = tk0 ? v2[1] : v2[0];
    int bp = t + (tk0 ? j2[1] : j2[0]) * 512;

    float wm = wave_max_f32(bv);
    unsigned wi = wave_min_u32(bv == wm ? (unsigned)bp : 0x7fffffffu);

    const int par = i & 1;
    if (lane == 0) { rv[par][w] = wm; ri[par][w] = (int)wi; }
    __syncthreads();
    float fv = rv[par][0]; int fi = ri[par][0];
#pragma unroll
    for (int q = 1; q < 8; ++q) {
      float qv = rv[par][q]; int qi = ri[par][q];
      if (qv > fv || (qv == fv && qi < fi)) { fv = qv; fi = qi; }
    }
    cx = xs[fi * 3 + 0]; cy = xs[fi * 3 + 1]; cz = xs[fi * 3 + 2];
    if (t == 0) {
      pts[((size_t)b * M_ + i) * 3 + 0] = cx;
      pts[((size_t)b * M_ + i) * 3 + 1] = cy;
      pts[((size_t)b * M_ + i) * 3 + 2] = cz;
    }
  }
}

// ---------------------------------------------------------------------------
// kNN (r1-verified scan; inner wave-argmin now DPP with identical tie rules)
// ---------------------------------------------------------------------------
template <int C>
__global__ __launch_bounds__(256) void knn_kernel(const float* __restrict__ f,
                                                  int* __restrict__ knn) {
  constexpr int C4 = (C + 3) / 4;
  __shared__ float4 ls4[C4 * 513];
  float* lss = (float*)ls4;
  const int b = blockIdx.x >> 4;
  const int mb = (blockIdx.x & 15) * 32;
  const int t = threadIdx.x, lane = t & 63, w = t >> 6;
  const float* fb = f + (size_t)b * M_ * C;
  if (C & 3) {
    for (int j = t; j < M_; j += 256)
      for (int cc = (C & 3); cc < 4; ++cc)
        lss[((C4 - 1) * 513 + j) * 4 + cc] = 0.f;
  }
  for (int s = t; s < M_ * C; s += 256) {
    int j = s / C, c = s % C;
    lss[((c >> 2) * 513 + j) * 4 + (c & 3)] = fb[s];
  }
  __syncthreads();

  float sqj[8];
#pragma unroll
  for (int jj = 0; jj < 8; ++jj) {
    int j = lane + 64 * jj;
    float a = 0.f;
    for (int c4 = 0; c4 < C4; ++c4) {
      float4 v = ls4[c4 * 513 + j];
      a += v.x * v.x + v.y * v.y + v.z * v.z + v.w * v.w;
    }
    sqj[jj] = a;
  }

  for (int rr = 0; rr < 8; ++rr) {
    const int m = mb + w * 8 + rr;
    float sqm = 0.f;
    for (int c4 = 0; c4 < C4; ++c4) {
      float4 v = ls4[c4 * 513 + m];
      sqm += v.x * v.x + v.y * v.y + v.z * v.z + v.w * v.w;
    }
    float dot[8] = {0.f, 0.f, 0.f, 0.f, 0.f, 0.f, 0.f, 0.f};
    for (int c4 = 0; c4 < C4; ++c4) {
      float4 fm = ls4[c4 * 513 + m];
#pragma unroll
      for (int jj = 0; jj < 8; ++jj) {
        float4 fj = ls4[c4 * 513 + lane + 64 * jj];
        dot[jj] += fm.x * fj.x + fm.y * fj.y + fm.z * fj.z + fm.w * fj.w;
      }
    }
    float d[8];
#pragma unroll
    for (int jj = 0; jj < 8; ++jj) d[jj] = (sqm - 2.f * dot[jj]) + sqj[jj];

    unsigned used = 0;
    int* out = knn + ((size_t)b * M_ + m) * KNB;
    for (int kk = 0; kk < KNB; ++kk) {
      float bv = __builtin_inff();
      int bi = 0x7fffffff;
#pragma unroll
      for (int jj = 0; jj < 8; ++jj) {
        if (!(used & (1u << jj))) {
          int j = lane + 64 * jj;
          if (d[jj] < bv || (d[jj] == bv && j < bi)) { bv = d[jj]; bi = j; }
        }
      }
      float wm = wave_min_f32(bv);
      unsigned wi = wave_min_u32(bv == wm ? (unsigned)bi : 0x7fffffffu);
      if (((int)wi & 63) == lane) used |= 1u << ((int)wi >> 6);
      if (lane == 0) out[kk] = (int)wi;
    }
  }
}

// ---------------------------------------------------------------------------
// Per-point projections, f32 (r4-verified): PC[p] = [ Pu | Cu | Pv | Cv ]
// ---------------------------------------------------------------------------
__global__ __launch_bounds__(256) void pointproj_kernel(
    const float* __restrict__ f, const float* __restrict__ Wq,
    const float* __restrict__ Wk, const float* __restrict__ Wv,
    float* __restrict__ PC, int C, int D) {
  __shared__ float As[16][68];
  __shared__ float Ws[16][68];
  const int t = threadIdx.x;
  const int r0 = blockIdx.x * 64, n0 = blockIdx.y * 64;
  const int tr = t >> 4, tc = t & 15;
  const int twoC = 2 * C;
  const int fourD = 4 * D;
  float acc[4][4] = {};
  const int Ksteps = (C + 15) / 16;
  for (int ks = 0; ks < Ksteps; ++ks) {
    int k0 = ks * 16;
#pragma unroll
    for (int s = 0; s < 4; ++s) {
      int id = t + s * 256;
      int kk = id & 15, rr = id >> 4;
      int c = k0 + kk;
      As[kk][rr] = (c < C) ? f[(size_t)(r0 + rr) * C + c] : 0.f;
      float wv = 0.f;
      if (c < C) {
        int n = n0 + rr;
        int reg = n / D, d = n % D;
        if (reg == 0)      wv = Wq[d * twoC + c] - Wk[d * twoC + c];
        else if (reg == 1) wv = (Wq[d * twoC + C + c] - Wk[d * twoC + C + c]) -
                                (Wq[d * twoC + c] - Wk[d * twoC + c]);
        else if (reg == 2) wv = Wv[d * twoC + c];
        else               wv = Wv[d * twoC + C + c] - Wv[d * twoC + c];
      }
      Ws[kk][rr] = wv;
    }
    __syncthreads();
#pragma unroll
    for (int kk = 0; kk < 16; ++kk) {
      float4 a = *(const float4*)&As[kk][tr * 4];
      float4 bq = *(const float4*)&Ws[kk][tc * 4];
      acc[0][0] += a.x * bq.x; acc[0][1] += a.x * bq.y; acc[0][2] += a.x * bq.z; acc[0][3] += a.x * bq.w;
      acc[1][0] += a.y * bq.x; acc[1][1] += a.y * bq.y; acc[1][2] += a.y * bq.z; acc[1][3] += a.y * bq.w;
      acc[2][0] += a.z * bq.x; acc[2][1] += a.z * bq.y; acc[2][2] += a.z * bq.z; acc[2][3] += a.z * bq.w;
      acc[3][0] += a.w * bq.x; acc[3][1] += a.w * bq.y; acc[3][2] += a.w * bq.z; acc[3][3] += a.w * bq.w;
    }
    __syncthreads();
  }
  const int col = n0 + tc * 4;
#pragma unroll
  for (int i = 0; i < 4; ++i) {
    int row = r0 + tr * 4 + i;
    float4 o; o.x = acc[i][0]; o.y = acc[i][1]; o.z = acc[i][2]; o.w = acc[i][3];
    *(float4*)&PC[(size_t)row * fourD + col] = o;
  }
}

// ---------------------------------------------------------------------------
// Weight split (3 matrices per layer, one launch): f32 -> bf16 hi + lo
// ---------------------------------------------------------------------------
__global__ void split3_w(const float* __restrict__ Wa, int na,
                         const float* __restrict__ Wb, int nb,
                         const float* __restrict__ Wc, int nc,
                         u16* __restrict__ Ah, u16* __restrict__ Al,
                         u16* __restrict__ Bh, u16* __restrict__ Bl,
                         u16* __restrict__ Ch, u16* __restrict__ Cl) {
  int k = blockIdx.x * 256 + threadIdx.x;
  const float* s; u16 *dh, *dl;
  if (k < na) { s = Wa; dh = Ah; dl = Al; }
  else if ((k -= na) < nb) { s = Wb; dh = Bh; dl = Bl; }
  else if ((k -= nb) < nc) { s = Wc; dh = Ch; dl = Cl; }
  else return;
  float v = s[k];
  u16 h = f2bf(v);
  dh[k] = h;
  dl[k] = f2bf(v - bf2f(h));
}

// ---------------------------------------------------------------------------
// Fused transformer layer (r5-verified)
// ---------------------------------------------------------------------------
template <int D, int H, int RB>
__global__ __launch_bounds__(256) void mega_kernel(
    const float* __restrict__ pts, const float* __restrict__ PC,
    const int* __restrict__ idx, const float* __restrict__ P1,
    const u16* __restrict__ P2h, const u16* __restrict__ P2l,
    const u16* __restrict__ A1h, const u16* __restrict__ A1l,
    const u16* __restrict__ A2h, const u16* __restrict__ A2l,
    float* __restrict__ xout) {
  constexpr int WC = D / 32;
  constexpr int HT = (RB == 64) ? 64 : 128;
  constexpr int WCa = HT / 32;
  constexpr int KCD = D / 8;
  constexpr int NIT = H / HT;
  constexpr int LSTR = RB + 1;
  constexpr int FD = 4 * D;

  __shared__ u32x4 sh_[KCD * LSTR], sl_[KCD * LSTR];
  __shared__ u32x4 xh_[KCD * LSTR], xl_[KCD * LSTR];
  __shared__ float upe[RB][D];
  __shared__ float rel4[RB][4];
  __shared__ int   nps[RB];
  __shared__ float P1s[D][4];

  const int t = threadIdx.x, lane = t & 63, w = t >> 6;
  const int kch = lane >> 4, lrow = lane & 15;
  const int r0g = blockIdx.x * RB;
  const int bm0 = r0g >> 4;

  if (t < RB) {
    int gr = r0g + t;
    int bb = gr >> 13;
    int np = bb * M_ + idx[gr];
    int bm = gr >> 4;
    nps[t] = np;
    rel4[t][0] = pts[np * 3 + 0] - pts[bm * 3 + 0];
    rel4[t][1] = pts[np * 3 + 1] - pts[bm * 3 + 1];
    rel4[t][2] = pts[np * 3 + 2] - pts[bm * 3 + 2];
  }
  for (int e = t; e < D * 4; e += 256) {
    int dd = e >> 2, c = e & 3;
    P1s[dd][c] = (c < 3) ? P1[dd * 3 + c] : 0.f;
  }
  __syncthreads();

  u16* xh_u = (u16*)xh_;
  u16* xl_u = (u16*)xl_;
  u16* sh_u = (u16*)sh_;
  u16* sl_u = (u16*)sl_;

#pragma unroll
  for (int i = 0; i < RB * D / 256; ++i) {
    int e = t + i * 256;
    int r = e / D, dd = e % D;
    int bm = bm0 + (r >> 4);
    int np = nps[r];
    upe[r][dd] = PC[(size_t)np * FD + dd] + PC[(size_t)bm * FD + D + dd];
    float hh = fmaxf(P1s[dd][0] * rel4[r][0] + P1s[dd][1] * rel4[r][1] +
                     P1s[dd][2] * rel4[r][2], 0.f);
    u16 hi = f2bf(hh), lo = f2bf(hh - bf2f(hi));
    int off = ((dd >> 3) * LSTR + r) * 8 + (dd & 7);
    xh_u[off] = hi; xl_u[off] = lo;
  }
  __syncthreads();

  const int wr2 = (w / WC) * 32, wc2 = (w % WC) * 32;

  {
    f32x4v pac[2][2];
#pragma unroll
    for (int a = 0; a < 2; ++a)
#pragma unroll
      for (int b = 0; b < 2; ++b) pac[a][b] = (f32x4v){0.f, 0.f, 0.f, 0.f};
#pragma unroll
    for (int k0 = 0; k0 < D; k0 += 32) {
      union { u32x4 u; short8 s; } ah[2], al[2], bh[2], bl[2];
#pragma unroll
      for (int fr = 0; fr < 2; ++fr) {
        int ai = ((k0 >> 3) + kch) * LSTR + wr2 + fr * 16 + lrow;
        ah[fr].u = xh_[ai]; al[fr].u = xl_[ai];
      }
#pragma unroll
      for (int fc = 0; fc < 2; ++fc) {
        size_t bi = (size_t)(wc2 + fc * 16 + lrow) * D + k0 + kch * 8;
        bh[fc].u = *(const u32x4*)(P2h + bi);
        bl[fc].u = *(const u32x4*)(P2l + bi);
      }
#pragma unroll
      for (int fr = 0; fr < 2; ++fr)
#pragma unroll
        for (int fc = 0; fc < 2; ++fc) {
          pac[fr][fc] = __builtin_amdgcn_mfma_f32_16x16x32_bf16(ah[fr].s, bh[fc].s, pac[fr][fc], 0, 0, 0);
          pac[fr][fc] = __builtin_amdgcn_mfma_f32_16x16x32_bf16(al[fr].s, bh[fc].s, pac[fr][fc], 0, 0, 0);
          pac[fr][fc] = __builtin_amdgcn_mfma_f32_16x16x32_bf16(ah[fr].s, bl[fc].s, pac[fr][fc], 0, 0, 0);
        }
    }
#pragma unroll
    for (int fr = 0; fr < 2; ++fr)
#pragma unroll
      for (int fc = 0; fc < 2; ++fc)
#pragma unroll
        for (int q = 0; q < 4; ++q) {
          int row = wr2 + fr * 16 + kch * 4 + q;
          int col = wc2 + fc * 16 + lrow;
          float pe = pac[fr][fc][q];
          float sv = pe + upe[row][col];
          upe[row][col] = pe;
          u16 hi = f2bf(sv), lo = f2bf(sv - bf2f(hi));
          int off = ((col >> 3) * LSTR + row) * 8 + (col & 7);
          sh_u[off] = hi; sl_u[off] = lo;
        }
  }
  __syncthreads();

  const int wra = (w / WCa) * 32, wca = (w % WCa) * 32;
  f32x4v lac[2][2];
#pragma unroll
  for (int a = 0; a < 2; ++a)
#pragma unroll
    for (int b = 0; b < 2; ++b) lac[a][b] = (f32x4v){0.f, 0.f, 0.f, 0.f};

#pragma unroll 1
  for (int it = 0; it < NIT; ++it) {
    const int hbase = it * HT;
    f32x4v aac[2][2];
#pragma unroll
    for (int a = 0; a < 2; ++a)
#pragma unroll
      for (int b = 0; b < 2; ++b) aac[a][b] = (f32x4v){0.f, 0.f, 0.f, 0.f};
#pragma unroll
    for (int k0 = 0; k0 < D; k0 += 32) {
      union { u32x4 u; short8 s; } ah[2], al[2], bh[2], bl[2];
#pragma unroll
      for (int fr = 0; fr < 2; ++fr) {
        int ai = ((k0 >> 3) + kch) * LSTR + wra + fr * 16 + lrow;
        ah[fr].u = sh_[ai]; al[fr].u = sl_[ai];
      }
#pragma unroll
      for (int fc = 0; fc < 2; ++fc) {
        size_t bi = (size_t)(hbase + wca + fc * 16 + lrow) * D + k0 + kch * 8;
        bh[fc].u = *(const u32x4*)(A1h + bi);
        bl[fc].u = *(const u32x4*)(A1l + bi);
      }
#pragma unroll
      for (int fr = 0; fr < 2; ++fr)
#pragma unroll
        for (int fc = 0; fc < 2; ++fc) {
          aac[fr][fc] = __builtin_amdgcn_mfma_f32_16x16x32_bf16(ah[fr].s, bh[fc].s, aac[fr][fc], 0, 0, 0);
          aac[fr][fc] = __builtin_amdgcn_mfma_f32_16x16x32_bf16(al[fr].s, bh[fc].s, aac[fr][fc], 0, 0, 0);
          aac[fr][fc] = __builtin_amdgcn_mfma_f32_16x16x32_bf16(ah[fr].s, bl[fc].s, aac[fr][fc], 0, 0, 0);
        }
    }
    __syncthreads();
#pragma unroll
    for (int fr = 0; fr < 2; ++fr)
#pragma unroll
      for (int fc = 0; fc < 2; ++fc)
#pragma unroll
        for (int q = 0; q < 4; ++q) {
          int row = wra + fr * 16 + kch * 4 + q;
          int ch = wca + fc * 16 + lrow;
          float av = fmaxf(aac[fr][fc][q], 0.f);
          u16 hi = f2bf(av), lo = f2bf(av - bf2f(hi));
          int off = ((ch >> 3) * LSTR + row) * 8 + (ch & 7);
          xh_u[off] = hi; xl_u[off] = lo;
        }
    __syncthreads();
#pragma unroll
    for (int k0 = 0; k0 < HT; k0 += 32) {
      union { u32x4 u; short8 s; } ah[2], al[2], bh[2], bl[2];
#pragma unroll
      for (int fr = 0; fr < 2; ++fr) {
        int ai = ((k0 >> 3) + kch) * LSTR + wr2 + fr * 16 + lrow;
        ah[fr].u = xh_[ai]; al[fr].u = xl_[ai];
      }
#pragma unroll
      for (int fc = 0; fc < 2; ++fc) {
        size_t bi = (size_t)(wc2 + fc * 16 + lrow) * H + hbase + k0 + kch * 8;
        bh[fc].u = *(const u32x4*)(A2h + bi);
        bl[fc].u = *(const u32x4*)(A2l + bi);
      }
#pragma unroll
      for (int fr = 0; fr < 2; ++fr)
#pragma unroll
        for (int fc = 0; fc < 2; ++fc) {
          lac[fr][fc] = __builtin_amdgcn_mfma_f32_16x16x32_bf16(ah[fr].s, bh[fc].s, lac[fr][fc], 0, 0, 0);
          lac[fr][fc] = __builtin_amdgcn_mfma_f32_16x16x32_bf16(al[fr].s, bh[fc].s, lac[fr][fc], 0, 0, 0);
          lac[fr][fc] = __builtin_amdgcn_mfma_f32_16x16x32_bf16(ah[fr].s, bl[fc].s, lac[fr][fc], 0, 0, 0);
        }
    }
  }

#pragma unroll
  for (int fr = 0; fr < 2; ++fr) {
    const int bmg = bm0 + ((wr2 + fr * 16) >> 4);
#pragma unroll
    for (int fc = 0; fc < 2; ++fc) {
      const int col = wc2 + fc * 16 + lrow;
      float lv[4];
#pragma unroll
      for (int q = 0; q < 4; ++q) lv[q] = lac[fr][fc][q];
      float mx = fmaxf(fmaxf(lv[0], lv[1]), fmaxf(lv[2], lv[3]));
      mx = fmaxf(mx, __shfl_xor(mx, 16));
      mx = fmaxf(mx, __shfl_xor(mx, 32));
      float ev[4];
      float ssum = 0.f;
#pragma unroll
      for (int q = 0; q < 4; ++q) { ev[q] = expf(lv[q] - mx); ssum += ev[q]; }
      ssum += __shfl_xor(ssum, 16);
      ssum += __shfl_xor(ssum, 32);
      float acc = 0.f;
#pragma unroll
      for (int q = 0; q < 4; ++q) {
        int row = wr2 + fr * 16 + kch * 4 + q;
        int np = nps[row];
        float vv = PC[(size_t)np * FD + 2 * D + col] + PC[(size_t)bmg * FD + 3 * D + col];
        acc += ev[q] * (vv + upe[row][col]);
      }
      acc += __shfl_xor(acc, 16);
      acc += __shfl_xor(acc, 32);
      if (kch == 0) xout[(size_t)bmg * D + col] = acc / ssum;
    }
  }
}

// ---------------------------------------------------------------------------
__global__ __launch_bounds__(256) void final_kernel(const float* __restrict__ x1,
                                                    const float* __restrict__ x2,
                                                    const float* __restrict__ x3,
                                                    float* __restrict__ out) {
  const int b = blockIdx.x, c = threadIdx.x;
  const float* p;
  int D, dc;
  if (c < 64)        { p = x1 + (size_t)b * M_ * 64;  D = 64;  dc = c; }
  else if (c < 128)  { p = x2 + (size_t)b * M_ * 64;  D = 64;  dc = c - 64; }
  else               { p = x3 + (size_t)b * M_ * 128; D = 128; dc = c - 128; }
  float mx = -__builtin_inff(), sm = 0.f;
  for (int m = 0; m < M_; ++m) {
    float v = p[(size_t)m * D + dc];
    mx = fmaxf(mx, v);
    sm += v;
  }
  out[(size_t)b * 512 + c] = mx;
  out[(size_t)b * 512 + 256 + c] = sm * (1.f / 512.f);
}

// ---------------------------------------------------------------------------
extern "C" void kernel_launch(void* const* d_in, const int* in_sizes, int n_in,
                              void* d_out, int out_size, void* d_ws, size_t ws_size,
                              hipStream_t stream) {
  const float* x = (const float*)d_in[0];
  const float* W[21];
  for (int i = 0; i < 21; ++i) W[i] = (const float*)d_in[1 + i];

  float* ws = (float*)d_ws;
  size_t off = 0;
  auto alloc = [&](size_t nfloats) { float* p = ws + off; off += nfloats; return p; };

  float* pts = alloc(24592);
  float* x1  = alloc((size_t)P_ * 64);
  float* x2  = alloc((size_t)P_ * 64);
  float* x3  = alloc((size_t)P_ * 128);
  int*   idxb = (int*)alloc((size_t)P_ * KNB);
  float* PC  = alloc((size_t)P_ * 512);    // [P][4D_max] f32
  u16* P2h = (u16*)alloc(8192);   u16* P2l = (u16*)alloc(8192);
  u16* A1h = (u16*)alloc(32768);  u16* A1l = (u16*)alloc(32768);
  u16* A2h = (u16*)alloc(32768);  u16* A2l = (u16*)alloc(32768);

  fps_kernel<<<B_, 512, 0, stream>>>(x, pts);

  struct Layer {
    const float* f; int C, D, H;
    const float *Wq, *Wk, *Wv, *P1, *P2, *A1, *A2;
    float* xout;
  };
  Layer ls[3] = {
      {pts, 3, 64, 256, W[0], W[1], W[2], W[3], W[4], W[5], W[6], x1},
      {x1, 64, 64, 256, W[7], W[8], W[9], W[10], W[11], W[12], W[13], x2},
      {x2, 64, 128, 512, W[14], W[15], W[16], W[17], W[18], W[19], W[20], x3},
  };

  for (int li = 0; li < 3; ++li) {
    const Layer& L = ls[li];
    if (L.C == 3) knn_kernel<3><<<B_ * 16, 256, 0, stream>>>(L.f, idxb);
    else          knn_kernel<64><<<B_ * 16, 256, 0, stream>>>(L.f, idxb);

    pointproj_kernel<<<dim3(P_ / 64, 4 * L.D / 64), 256, 0, stream>>>(
        L.f, L.Wq, L.Wk, L.Wv, PC, L.C, L.D);

    int nP2 = L.D * L.D, nA1 = L.H * L.D, nA2 = L.D * L.H;
    split3_w<<<(nP2 + nA1 + nA2 + 255) / 256, 256, 0, stream>>>(
        L.P2, nP2, L.A1, nA1, L.A2, nA2, P2h, P2l, A1h, A1l, A2h, A2l);

    if (L.D == 64)
      mega_kernel<64, 256, 64><<<ROWS_ / 64, 256, 0, stream>>>(
          pts, PC, idxb, L.P1, P2h, P2l, A1h, A1l, A2h, A2l, L.xout);
    else
      mega_kernel<128, 512, 32><<<ROWS_ / 32, 256, 0, stream>>>(
          pts, PC, idxb, L.P1, P2h, P2l, A1h, A1l, A2h, A2l, L.xout);
  }

  final_kernel<<<B_, 256, 0, stream>>>(x1, x2, x3, (float*)d_out);
}

// Round 8
// 1312.296 us; speedup vs baseline: 2.6202x; 1.0948x over previous
//
#include <hip/hip_runtime.h>
#include <cstdint>
#include <cstddef>

#define B_  16
#define N_  4096
#define M_  512
#define KNB 16
#define P_  (B_ * M_)
#define ROWS_ (B_ * M_ * KNB)   // 131072

typedef unsigned short u16;
typedef unsigned long long u64;
typedef __attribute__((ext_vector_type(4))) unsigned int u32x4;
typedef __attribute__((ext_vector_type(8))) short short8;
typedef __attribute__((ext_vector_type(4))) float f32x4v;

__device__ inline u16 f2bf(float f) {
  union { float f; unsigned u; } x; x.f = f;
  unsigned r = x.u + 0x7fffu + ((x.u >> 16) & 1u);
  return (u16)(r >> 16);
}
__device__ inline float bf2f(u16 h) {
  union { unsigned u; float f; } x; x.u = ((unsigned)h) << 16;
  return x.f;
}

// ---------------------------------------------------------------------------
// Packed-u64 wave reductions via DPP (row_shr 1/2/4/8 + row_bcast 15/31).
// ---------------------------------------------------------------------------
__device__ inline u64 wave_max_u64(u64 k) {
#define STEP64MAX(ctrl)                                                               \
  {                                                                                   \
    unsigned olo = (unsigned)__builtin_amdgcn_update_dpp(0, (int)(unsigned)k, ctrl, 0xf, 0xf, false); \
    unsigned ohi = (unsigned)__builtin_amdgcn_update_dpp(0, (int)(unsigned)(k >> 32), ctrl, 0xf, 0xf, false); \
    u64 o = ((u64)ohi << 32) | olo;                                                   \
    k = o > k ? o : k;                                                                \
  }
  STEP64MAX(0x111) STEP64MAX(0x112) STEP64MAX(0x114) STEP64MAX(0x118)
  STEP64MAX(0x142) STEP64MAX(0x143)
#undef STEP64MAX
  unsigned rlo = (unsigned)__builtin_amdgcn_readlane((int)(unsigned)k, 63);
  unsigned rhi = (unsigned)__builtin_amdgcn_readlane((int)(unsigned)(k >> 32), 63);
  return ((u64)rhi << 32) | rlo;
}
__device__ inline u64 wave_min_u64(u64 k) {
#define STEP64MIN(ctrl)                                                               \
  {                                                                                   \
    unsigned olo = (unsigned)__builtin_amdgcn_update_dpp(-1, (int)(unsigned)k, ctrl, 0xf, 0xf, false); \
    unsigned ohi = (unsigned)__builtin_amdgcn_update_dpp(-1, (int)(unsigned)(k >> 32), ctrl, 0xf, 0xf, false); \
    u64 o = ((u64)ohi << 32) | olo;                                                   \
    k = o < k ? o : k;                                                                \
  }
  STEP64MIN(0x111) STEP64MIN(0x112) STEP64MIN(0x114) STEP64MIN(0x118)
  STEP64MIN(0x142) STEP64MIN(0x143)
#undef STEP64MIN
  unsigned rlo = (unsigned)__builtin_amdgcn_readlane((int)(unsigned)k, 63);
  unsigned rhi = (unsigned)__builtin_amdgcn_readlane((int)(unsigned)(k >> 32), 63);
  return ((u64)rhi << 32) | rlo;
}

// ---------------------------------------------------------------------------
// FPS: 512 threads, 8 pts/lane. key=(fbits<<32)|~p (dists >= 0) -> pure u64 max.
// Cross-wave stage reads ALL 8 wave keys (64 bytes; r7 bug read only 32).
// Distance arithmetic bit-identical to the r4-verified chain.
// ---------------------------------------------------------------------------
__global__ __launch_bounds__(512) void fps_kernel(const float* __restrict__ x,
                                                  float* __restrict__ pts) {
  __shared__ float4 xs4[N_];
  __shared__ __align__(16) u64 rv64[2][8];
  const int b = blockIdx.x, t = threadIdx.x, lane = t & 63, w = t >> 6;
  const float* xb = x + (size_t)b * N_ * 3;
  for (int p = t; p < N_; p += 512) {
    const float* s = xb + p * 3;
    xs4[p] = make_float4(s[0], s[1], s[2], 0.f);
  }
  __syncthreads();

  float px[8], py[8], pz[8], dm[8];
#pragma unroll
  for (int j = 0; j < 8; ++j) {
    float4 v = xs4[t + j * 512];
    px[j] = v.x; py[j] = v.y; pz[j] = v.z;
    dm[j] = __builtin_inff();
  }
  float cx = xs4[0].x, cy = xs4[0].y, cz = xs4[0].z;
  if (t == 0) {
    pts[(size_t)b * M_ * 3 + 0] = cx;
    pts[(size_t)b * M_ * 3 + 1] = cy;
    pts[(size_t)b * M_ * 3 + 2] = cz;
  }
  for (int i = 1; i < M_; ++i) {
    u64 kk8[8];
#pragma unroll
    for (int j = 0; j < 8; ++j) {
      float dx = px[j] - cx, dy = py[j] - cy, dz = pz[j] - cz;
      float dd = __fmul_rn(dx, dx);
      dd = __fadd_rn(dd, __fmul_rn(dy, dy));
      dd = __fadd_rn(dd, __fmul_rn(dz, dz));
      dd = fminf(dm[j], dd);
      dm[j] = dd;
      kk8[j] = ((u64)__float_as_uint(dd) << 32) | (unsigned)(~(t + j * 512));
    }
    u64 k4[4], k2[2], kb;
#pragma unroll
    for (int j = 0; j < 4; ++j) k4[j] = kk8[j] > kk8[j + 4] ? kk8[j] : kk8[j + 4];
#pragma unroll
    for (int j = 0; j < 2; ++j) k2[j] = k4[j] > k4[j + 2] ? k4[j] : k4[j + 2];
    kb = k2[0] > k2[1] ? k2[0] : k2[1];
    kb = wave_max_u64(kb);

    const int par = i & 1;
    if (lane == 0) rv64[par][w] = kb;
    __syncthreads();
    u32x4 a0 = *(const u32x4*)&rv64[par][0];   // keys 0,1
    u32x4 a1 = *(const u32x4*)&rv64[par][2];   // keys 2,3
    u32x4 a2 = *(const u32x4*)&rv64[par][4];   // keys 4,5
    u32x4 a3 = *(const u32x4*)&rv64[par][6];   // keys 6,7
    u64 q0 = ((u64)a0[1] << 32) | a0[0];
    u64 q1 = ((u64)a0[3] << 32) | a0[2];
    u64 q2 = ((u64)a1[1] << 32) | a1[0];
    u64 q3 = ((u64)a1[3] << 32) | a1[2];
    u64 q4 = ((u64)a2[1] << 32) | a2[0];
    u64 q5 = ((u64)a2[3] << 32) | a2[2];
    u64 q6 = ((u64)a3[1] << 32) | a3[0];
    u64 q7 = ((u64)a3[3] << 32) | a3[2];
    u64 m0 = q0 > q1 ? q0 : q1;
    u64 m1 = q2 > q3 ? q2 : q3;
    u64 m2 = q4 > q5 ? q4 : q5;
    u64 m3 = q6 > q7 ? q6 : q7;
    u64 n0 = m0 > m1 ? m0 : m1;
    u64 n1 = m2 > m3 ? m2 : m3;
    u64 km = n0 > n1 ? n0 : n1;
    int fi = (int)(~(unsigned)km) & (N_ - 1);
    float4 cc = xs4[fi];
    cx = cc.x; cy = cc.y; cz = cc.z;
    if (t == 0) {
      pts[((size_t)b * M_ + i) * 3 + 0] = cx;
      pts[((size_t)b * M_ + i) * 3 + 1] = cy;
      pts[((size_t)b * M_ + i) * 3 + 2] = cz;
    }
  }
}

// ---------------------------------------------------------------------------
// kNN: r1-verified scan/staging; top-16 rounds use packed-u64 min keys.
// ---------------------------------------------------------------------------
template <int C>
__global__ __launch_bounds__(256) void knn_kernel(const float* __restrict__ f,
                                                  int* __restrict__ knn) {
  constexpr int C4 = (C + 3) / 4;
  __shared__ float4 ls4[C4 * 513];
  float* lss = (float*)ls4;
  const int b = blockIdx.x >> 4;
  const int mb = (blockIdx.x & 15) * 32;
  const int t = threadIdx.x, lane = t & 63, w = t >> 6;
  const float* fb = f + (size_t)b * M_ * C;
  if (C & 3) {
    for (int j = t; j < M_; j += 256)
      for (int cc = (C & 3); cc < 4; ++cc)
        lss[((C4 - 1) * 513 + j) * 4 + cc] = 0.f;
  }
  for (int s = t; s < M_ * C; s += 256) {
    int j = s / C, c = s % C;
    lss[((c >> 2) * 513 + j) * 4 + (c & 3)] = fb[s];
  }
  __syncthreads();

  float sqj[8];
#pragma unroll
  for (int jj = 0; jj < 8; ++jj) {
    int j = lane + 64 * jj;
    float a = 0.f;
    for (int c4 = 0; c4 < C4; ++c4) {
      float4 v = ls4[c4 * 513 + j];
      a += v.x * v.x + v.y * v.y + v.z * v.z + v.w * v.w;
    }
    sqj[jj] = a;
  }

  for (int rr = 0; rr < 8; ++rr) {
    const int m = mb + w * 8 + rr;
    float sqm = 0.f;
    for (int c4 = 0; c4 < C4; ++c4) {
      float4 v = ls4[c4 * 513 + m];
      sqm += v.x * v.x + v.y * v.y + v.z * v.z + v.w * v.w;
    }
    float dot[8] = {0.f, 0.f, 0.f, 0.f, 0.f, 0.f, 0.f, 0.f};
    for (int c4 = 0; c4 < C4; ++c4) {
      float4 fm = ls4[c4 * 513 + m];
#pragma unroll
      for (int jj = 0; jj < 8; ++jj) {
        float4 fj = ls4[c4 * 513 + lane + 64 * jj];
        dot[jj] += fm.x * fj.x + fm.y * fj.y + fm.z * fj.z + fm.w * fj.w;
      }
    }
    u64 mk[8];
#pragma unroll
    for (int jj = 0; jj < 8; ++jj) {
      float d = (sqm - 2.f * dot[jj]) + sqj[jj];
      unsigned um = __float_as_uint(d);
      um = (um >> 31) ? ~um : (um | 0x80000000u);   // order-preserving f32->u32
      mk[jj] = ((u64)um << 32) | (unsigned)(lane + 64 * jj);
    }

    int* out = knn + ((size_t)b * M_ + m) * KNB;
    for (int kk = 0; kk < KNB; ++kk) {
      u64 k4[4], k2[2], kb;
#pragma unroll
      for (int jj = 0; jj < 4; ++jj) k4[jj] = mk[jj] < mk[jj + 4] ? mk[jj] : mk[jj + 4];
#pragma unroll
      for (int jj = 0; jj < 2; ++jj) k2[jj] = k4[jj] < k4[jj + 2] ? k4[jj] : k4[jj + 2];
      kb = k2[0] < k2[1] ? k2[0] : k2[1];
      kb = wave_min_u64(kb);
      int j = (int)(unsigned)kb;
      if ((j & 63) == lane) mk[j >> 6] = ~0ull;
      if (lane == 0) out[kk] = j;
    }
  }
}

// ---------------------------------------------------------------------------
// Per-point projections, f32 (r4-verified): PC[p] = [ Pu | Cu | Pv | Cv ]
// ---------------------------------------------------------------------------
__global__ __launch_bounds__(256) void pointproj_kernel(
    const float* __restrict__ f, const float* __restrict__ Wq,
    const float* __restrict__ Wk, const float* __restrict__ Wv,
    float* __restrict__ PC, int C, int D) {
  __shared__ float As[16][68];
  __shared__ float Ws[16][68];
  const int t = threadIdx.x;
  const int r0 = blockIdx.x * 64, n0 = blockIdx.y * 64;
  const int tr = t >> 4, tc = t & 15;
  const int twoC = 2 * C;
  const int fourD = 4 * D;
  float acc[4][4] = {};
  const int Ksteps = (C + 15) / 16;
  for (int ks = 0; ks < Ksteps; ++ks) {
    int k0 = ks * 16;
#pragma unroll
    for (int s = 0; s < 4; ++s) {
      int id = t + s * 256;
      int kk = id & 15, rr = id >> 4;
      int c = k0 + kk;
      As[kk][rr] = (c < C) ? f[(size_t)(r0 + rr) * C + c] : 0.f;
      float wv = 0.f;
      if (c < C) {
        int n = n0 + rr;
        int reg = n / D, d = n % D;
        if (reg == 0)      wv = Wq[d * twoC + c] - Wk[d * twoC + c];
        else if (reg == 1) wv = (Wq[d * twoC + C + c] - Wk[d * twoC + C + c]) -
                                (Wq[d * twoC + c] - Wk[d * twoC + c]);
        else if (reg == 2) wv = Wv[d * twoC + c];
        else               wv = Wv[d * twoC + C + c] - Wv[d * twoC + c];
      }
      Ws[kk][rr] = wv;
    }
    __syncthreads();
#pragma unroll
    for (int kk = 0; kk < 16; ++kk) {
      float4 a = *(const float4*)&As[kk][tr * 4];
      float4 bq = *(const float4*)&Ws[kk][tc * 4];
      acc[0][0] += a.x * bq.x; acc[0][1] += a.x * bq.y; acc[0][2] += a.x * bq.z; acc[0][3] += a.x * bq.w;
      acc[1][0] += a.y * bq.x; acc[1][1] += a.y * bq.y; acc[1][2] += a.y * bq.z; acc[1][3] += a.y * bq.w;
      acc[2][0] += a.z * bq.x; acc[2][1] += a.z * bq.y; acc[2][2] += a.z * bq.z; acc[2][3] += a.z * bq.w;
      acc[3][0] += a.w * bq.x; acc[3][1] += a.w * bq.y; acc[3][2] += a.w * bq.z; acc[3][3] += a.w * bq.w;
    }
    __syncthreads();
  }
  const int col = n0 + tc * 4;
#pragma unroll
  for (int i = 0; i < 4; ++i) {
    int row = r0 + tr * 4 + i;
    float4 o; o.x = acc[i][0]; o.y = acc[i][1]; o.z = acc[i][2]; o.w = acc[i][3];
    *(float4*)&PC[(size_t)row * fourD + col] = o;
  }
}

// ---------------------------------------------------------------------------
// Weight split (3 matrices per layer, one launch): f32 -> bf16 hi + lo
// ---------------------------------------------------------------------------
__global__ void split3_w(const float* __restrict__ Wa, int na,
                         const float* __restrict__ Wb, int nb,
                         const float* __restrict__ Wc, int nc,
                         u16* __restrict__ Ah, u16* __restrict__ Al,
                         u16* __restrict__ Bh, u16* __restrict__ Bl,
                         u16* __restrict__ Ch, u16* __restrict__ Cl) {
  int k = blockIdx.x * 256 + threadIdx.x;
  const float* s; u16 *dh, *dl;
  if (k < na) { s = Wa; dh = Ah; dl = Al; }
  else if ((k -= na) < nb) { s = Wb; dh = Bh; dl = Bl; }
  else if ((k -= nb) < nc) { s = Wc; dh = Ch; dl = Cl; }
  else return;
  float v = s[k];
  u16 h = f2bf(v);
  dh[k] = h;
  dl[k] = f2bf(v - bf2f(h));
}

// ---------------------------------------------------------------------------
// Fused transformer layer (r5/r6-verified)
// ---------------------------------------------------------------------------
template <int D, int H, int RB>
__global__ __launch_bounds__(256) void mega_kernel(
    const float* __restrict__ pts, const float* __restrict__ PC,
    const int* __restrict__ idx, const float* __restrict__ P1,
    const u16* __restrict__ P2h, const u16* __restrict__ P2l,
    const u16* __restrict__ A1h, const u16* __restrict__ A1l,
    const u16* __restrict__ A2h, const u16* __restrict__ A2l,
    float* __restrict__ xout) {
  constexpr int WC = D / 32;
  constexpr int HT = (RB == 64) ? 64 : 128;
  constexpr int WCa = HT / 32;
  constexpr int KCD = D / 8;
  constexpr int NIT = H / HT;
  constexpr int LSTR = RB + 1;
  constexpr int FD = 4 * D;

  __shared__ u32x4 sh_[KCD * LSTR], sl_[KCD * LSTR];
  __shared__ u32x4 xh_[KCD * LSTR], xl_[KCD * LSTR];
  __shared__ float upe[RB][D];
  __shared__ float rel4[RB][4];
  __shared__ int   nps[RB];
  __shared__ float P1s[D][4];

  const int t = threadIdx.x, lane = t & 63, w = t >> 6;
  const int kch = lane >> 4, lrow = lane & 15;
  const int r0g = blockIdx.x * RB;
  const int bm0 = r0g >> 4;

  if (t < RB) {
    int gr = r0g + t;
    int bb = gr >> 13;
    int np = bb * M_ + idx[gr];
    int bm = gr >> 4;
    nps[t] = np;
    rel4[t][0] = pts[np * 3 + 0] - pts[bm * 3 + 0];
    rel4[t][1] = pts[np * 3 + 1] - pts[bm * 3 + 1];
    rel4[t][2] = pts[np * 3 + 2] - pts[bm * 3 + 2];
  }
  for (int e = t; e < D * 4; e += 256) {
    int dd = e >> 2, c = e & 3;
    P1s[dd][c] = (c < 3) ? P1[dd * 3 + c] : 0.f;
  }
  __syncthreads();

  u16* xh_u = (u16*)xh_;
  u16* xl_u = (u16*)xl_;
  u16* sh_u = (u16*)sh_;
  u16* sl_u = (u16*)sl_;

#pragma unroll
  for (int i = 0; i < RB * D / 256; ++i) {
    int e = t + i * 256;
    int r = e / D, dd = e % D;
    int bm = bm0 + (r >> 4);
    int np = nps[r];
    upe[r][dd] = PC[(size_t)np * FD + dd] + PC[(size_t)bm * FD + D + dd];
    float hh = fmaxf(P1s[dd][0] * rel4[r][0] + P1s[dd][1] * rel4[r][1] +
                     P1s[dd][2] * rel4[r][2], 0.f);
    u16 hi = f2bf(hh), lo = f2bf(hh - bf2f(hi));
    int off = ((dd >> 3) * LSTR + r) * 8 + (dd & 7);
    xh_u[off] = hi; xl_u[off] = lo;
  }
  __syncthreads();

  const int wr2 = (w / WC) * 32, wc2 = (w % WC) * 32;

  {
    f32x4v pac[2][2];
#pragma unroll
    for (int a = 0; a < 2; ++a)
#pragma unroll
      for (int b = 0; b < 2; ++b) pac[a][b] = (f32x4v){0.f, 0.f, 0.f, 0.f};
#pragma unroll
    for (int k0 = 0; k0 < D; k0 += 32) {
      union { u32x4 u; short8 s; } ah[2], al[2], bh[2], bl[2];
#pragma unroll
      for (int fr = 0; fr < 2; ++fr) {
        int ai = ((k0 >> 3) + kch) * LSTR + wr2 + fr * 16 + lrow;
        ah[fr].u = xh_[ai]; al[fr].u = xl_[ai];
      }
#pragma unroll
      for (int fc = 0; fc < 2; ++fc) {
        size_t bi = (size_t)(wc2 + fc * 16 + lrow) * D + k0 + kch * 8;
        bh[fc].u = *(const u32x4*)(P2h + bi);
        bl[fc].u = *(const u32x4*)(P2l + bi);
      }
#pragma unroll
      for (int fr = 0; fr < 2; ++fr)
#pragma unroll
        for (int fc = 0; fc < 2; ++fc) {
          pac[fr][fc] = __builtin_amdgcn_mfma_f32_16x16x32_bf16(ah[fr].s, bh[fc].s, pac[fr][fc], 0, 0, 0);
          pac[fr][fc] = __builtin_amdgcn_mfma_f32_16x16x32_bf16(al[fr].s, bh[fc].s, pac[fr][fc], 0, 0, 0);
          pac[fr][fc] = __builtin_amdgcn_mfma_f32_16x16x32_bf16(ah[fr].s, bl[fc].s, pac[fr][fc], 0, 0, 0);
        }
    }
#pragma unroll
    for (int fr = 0; fr < 2; ++fr)
#pragma unroll
      for (int fc = 0; fc < 2; ++fc)
#pragma unroll
        for (int q = 0; q < 4; ++q) {
          int row = wr2 + fr * 16 + kch * 4 + q;
          int col = wc2 + fc * 16 + lrow;
          float pe = pac[fr][fc][q];
          float sv = pe + upe[row][col];
          upe[row][col] = pe;
          u16 hi = f2bf(sv), lo = f2bf(sv - bf2f(hi));
          int off = ((col >> 3) * LSTR + row) * 8 + (col & 7);
          sh_u[off] = hi; sl_u[off] = lo;
        }
  }
  __syncthreads();

  const int wra = (w / WCa) * 32, wca = (w % WCa) * 32;
  f32x4v lac[2][2];
#pragma unroll
  for (int a = 0; a < 2; ++a)
#pragma unroll
    for (int b = 0; b < 2; ++b) lac[a][b] = (f32x4v){0.f, 0.f, 0.f, 0.f};

#pragma unroll 1
  for (int it = 0; it < NIT; ++it) {
    const int hbase = it * HT;
    f32x4v aac[2][2];
#pragma unroll
    for (int a = 0; a < 2; ++a)
#pragma unroll
      for (int b = 0; b < 2; ++b) aac[a][b] = (f32x4v){0.f, 0.f, 0.f, 0.f};
#pragma unroll
    for (int k0 = 0; k0 < D; k0 += 32) {
      union { u32x4 u; short8 s; } ah[2], al[2], bh[2], bl[2];
#pragma unroll
      for (int fr = 0; fr < 2; ++fr) {
        int ai = ((k0 >> 3) + kch) * LSTR + wra + fr * 16 + lrow;
        ah[fr].u = sh_[ai]; al[fr].u = sl_[ai];
      }
#pragma unroll
      for (int fc = 0; fc < 2; ++fc) {
        size_t bi = (size_t)(hbase + wca + fc * 16 + lrow) * D + k0 + kch * 8;
        bh[fc].u = *(const u32x4*)(A1h + bi);
        bl[fc].u = *(const u32x4*)(A1l + bi);
      }
#pragma unroll
      for (int fr = 0; fr < 2; ++fr)
#pragma unroll
        for (int fc = 0; fc < 2; ++fc) {
          aac[fr][fc] = __builtin_amdgcn_mfma_f32_16x16x32_bf16(ah[fr].s, bh[fc].s, aac[fr][fc], 0, 0, 0);
          aac[fr][fc] = __builtin_amdgcn_mfma_f32_16x16x32_bf16(al[fr].s, bh[fc].s, aac[fr][fc], 0, 0, 0);
          aac[fr][fc] = __builtin_amdgcn_mfma_f32_16x16x32_bf16(ah[fr].s, bl[fc].s, aac[fr][fc], 0, 0, 0);
        }
    }
    __syncthreads();
#pragma unroll
    for (int fr = 0; fr < 2; ++fr)
#pragma unroll
      for (int fc = 0; fc < 2; ++fc)
#pragma unroll
        for (int q = 0; q < 4; ++q) {
          int row = wra + fr * 16 + kch * 4 + q;
          int ch = wca + fc * 16 + lrow;
          float av = fmaxf(aac[fr][fc][q], 0.f);
          u16 hi = f2bf(av), lo = f2bf(av - bf2f(hi));
          int off = ((ch >> 3) * LSTR + row) * 8 + (ch & 7);
          xh_u[off] = hi; xl_u[off] = lo;
        }
    __syncthreads();
#pragma unroll
    for (int k0 = 0; k0 < HT; k0 += 32) {
      union { u32x4 u; short8 s; } ah[2], al[2], bh[2], bl[2];
#pragma unroll
      for (int fr = 0; fr < 2; ++fr) {
        int ai = ((k0 >> 3) + kch) * LSTR + wr2 + fr * 16 + lrow;
        ah[fr].u = xh_[ai]; al[fr].u = xl_[ai];
      }
#pragma unroll
      for (int fc = 0; fc < 2; ++fc) {
        size_t bi = (size_t)(wc2 + fc * 16 + lrow) * H + hbase + k0 + kch * 8;
        bh[fc].u = *(const u32x4*)(A2h + bi);
        bl[fc].u = *(const u32x4*)(A2l + bi);
      }
#pragma unroll
      for (int fr = 0; fr < 2; ++fr)
#pragma unroll
        for (int fc = 0; fc < 2; ++fc) {
          lac[fr][fc] = __builtin_amdgcn_mfma_f32_16x16x32_bf16(ah[fr].s, bh[fc].s, lac[fr][fc], 0, 0, 0);
          lac[fr][fc] = __builtin_amdgcn_mfma_f32_16x16x32_bf16(al[fr].s, bh[fc].s, lac[fr][fc], 0, 0, 0);
          lac[fr][fc] = __builtin_amdgcn_mfma_f32_16x16x32_bf16(ah[fr].s, bl[fc].s, lac[fr][fc], 0, 0, 0);
        }
    }
  }

#pragma unroll
  for (int fr = 0; fr < 2; ++fr) {
    const int bmg = bm0 + ((wr2 + fr * 16) >> 4);
#pragma unroll
    for (int fc = 0; fc < 2; ++fc) {
      const int col = wc2 + fc * 16 + lrow;
      float lv[4];
#pragma unroll
      for (int q = 0; q < 4; ++q) lv[q] = lac[fr][fc][q];
      float mx = fmaxf(fmaxf(lv[0], lv[1]), fmaxf(lv[2], lv[3]));
      mx = fmaxf(mx, __shfl_xor(mx, 16));
      mx = fmaxf(mx, __shfl_xor(mx, 32));
      float ev[4];
      float ssum = 0.f;
#pragma unroll
      for (int q = 0; q < 4; ++q) { ev[q] = expf(lv[q] - mx); ssum += ev[q]; }
      ssum += __shfl_xor(ssum, 16);
      ssum += __shfl_xor(ssum, 32);
      float acc = 0.f;
#pragma unroll
      for (int q = 0; q < 4; ++q) {
        int row = wr2 + fr * 16 + kch * 4 + q;
        int np = nps[row];
        float vv = PC[(size_t)np * FD + 2 * D + col] + PC[(size_t)bmg * FD + 3 * D + col];
        acc += ev[q] * (vv + upe[row][col]);
      }
      acc += __shfl_xor(acc, 16);
      acc += __shfl_xor(acc, 32);
      if (kch == 0) xout[(size_t)bmg * D + col] = acc / ssum;
    }
  }
}

// ---------------------------------------------------------------------------
__global__ __launch_bounds__(256) void final_kernel(const float* __restrict__ x1,
                                                    const float* __restrict__ x2,
                                                    const float* __restrict__ x3,
                                                    float* __restrict__ out) {
  const int b = blockIdx.x, c = threadIdx.x;
  const float* p;
  int D, dc;
  if (c < 64)        { p = x1 + (size_t)b * M_ * 64;  D = 64;  dc = c; }
  else if (c < 128)  { p = x2 + (size_t)b * M_ * 64;  D = 64;  dc = c - 64; }
  else               { p = x3 + (size_t)b * M_ * 128; D = 128; dc = c - 128; }
  float mx = -__builtin_inff(), sm = 0.f;
  for (int m = 0; m < M_; ++m) {
    float v = p[(size_t)m * D + dc];
    mx = fmaxf(mx, v);
    sm += v;
  }
  out[(size_t)b * 512 + c] = mx;
  out[(size_t)b * 512 + 256 + c] = sm * (1.f / 512.f);
}

// ---------------------------------------------------------------------------
extern "C" void kernel_launch(void* const* d_in, const int* in_sizes, int n_in,
                              void* d_out, int out_size, void* d_ws, size_t ws_size,
                              hipStream_t stream) {
  const float* x = (const float*)d_in[0];
  const float* W[21];
  for (int i = 0; i < 21; ++i) W[i] = (const float*)d_in[1 + i];

  float* ws = (float*)d_ws;
  size_t off = 0;
  auto alloc = [&](size_t nfloats) { float* p = ws + off; off += nfloats; return p; };

  float* pts = alloc(24592);
  float* x1  = alloc((size_t)P_ * 64);
  float* x2  = alloc((size_t)P_ * 64);
  float* x3  = alloc((size_t)P_ * 128);
  int*   idxb = (int*)alloc((size_t)P_ * KNB);
  float* PC  = alloc((size_t)P_ * 512);    // [P][4D_max] f32
  u16* P2h = (u16*)alloc(8192);   u16* P2l = (u16*)alloc(8192);
  u16* A1h = (u16*)alloc(32768);  u16* A1l = (u16*)alloc(32768);
  u16* A2h = (u16*)alloc(32768);  u16* A2l = (u16*)alloc(32768);

  fps_kernel<<<B_, 512, 0, stream>>>(x, pts);

  struct Layer {
    const float* f; int C, D, H;
    const float *Wq, *Wk, *Wv, *P1, *P2, *A1, *A2;
    float* xout;
  };
  Layer ls[3] = {
      {pts, 3, 64, 256, W[0], W[1], W[2], W[3], W[4], W[5], W[6], x1},
      {x1, 64, 64, 256, W[7], W[8], W[9], W[10], W[11], W[12], W[13], x2},
      {x2, 64, 128, 512, W[14], W[15], W[16], W[17], W[18], W[19], W[20], x3},
  };

  for (int li = 0; li < 3; ++li) {
    const Layer& L = ls[li];
    if (L.C == 3) knn_kernel<3><<<B_ * 16, 256, 0, stream>>>(L.f, idxb);
    else          knn_kernel<64><<<B_ * 16, 256, 0, stream>>>(L.f, idxb);

    pointproj_kernel<<<dim3(P_ / 64, 4 * L.D / 64), 256, 0, stream>>>(
        L.f, L.Wq, L.Wk, L.Wv, PC, L.C, L.D);

    int nP2 = L.D * L.D, nA1 = L.H * L.D, nA2 = L.D * L.H;
    split3_w<<<(nP2 + nA1 + nA2 + 255) / 256, 256, 0, stream>>>(
        L.P2, nP2, L.A1, nA1, L.A2, nA2, P2h, P2l, A1h, A1l, A2h, A2l);

    if (L.D == 64)
      mega_kernel<64, 256, 64><<<ROWS_ / 64, 256, 0, stream>>>(
          pts, PC, idxb, L.P1, P2h, P2l, A1h, A1l, A2h, A2l, L.xout);
    else
      mega_kernel<128, 512, 32><<<ROWS_ / 32, 256, 0, stream>>>(
          pts, PC, idxb, L.P1, P2h, P2l, A1h, A1l, A2h, A2l, L.xout);
  }

  final_kernel<<<B_, 256, 0, stream>>>(x1, x2, x3, (float*)d_out);
}